// Round 10
// baseline (2705.772 us; speedup 1.0000x reference)
//
#include <hip/hip_runtime.h>
#include <hip/hip_bf16.h>

typedef __attribute__((ext_vector_type(8))) __bf16 bf16x8;
typedef __attribute__((ext_vector_type(4))) float floatx4;

typedef __attribute__((address_space(1))) const unsigned char kGlb;
typedef __attribute__((address_space(3))) unsigned char kLds;

static constexpr int S = 2048;
static constexpr int D = 2048;
static constexpr int HD = 256;
static constexpr int NH = 8;
static constexpr int NKV = 4;
static constexpr int NLAYER = 4;
static constexpr int VOCAB = 32000;
static constexpr int FF = 8192;
static constexpr int WINDOW = 1024;

// ---------------- block reduction helpers (256 threads = 4 waves) ----------------
__device__ __forceinline__ float blk_sum(float v) {
    __shared__ float sm[4];
    #pragma unroll
    for (int o = 32; o > 0; o >>= 1) v += __shfl_down(v, o, 64);
    int lane = threadIdx.x & 63, w = threadIdx.x >> 6;
    __syncthreads();
    if (lane == 0) sm[w] = v;
    __syncthreads();
    return sm[0] + sm[1] + sm[2] + sm[3];
}

__device__ __forceinline__ float blk_max(float v) {
    __shared__ float sm[4];
    #pragma unroll
    for (int o = 32; o > 0; o >>= 1) v = fmaxf(v, __shfl_down(v, o, 64));
    int lane = threadIdx.x & 63, w = threadIdx.x >> 6;
    __syncthreads();
    if (lane == 0) sm[w] = v;
    __syncthreads();
    return fmaxf(fmaxf(sm[0], sm[1]), fmaxf(sm[2], sm[3]));
}

// ---------------- elementwise kernels ----------------
__global__ void embed_kernel(const int* __restrict__ ids, const float* __restrict__ E,
                             float* __restrict__ h) {
    int d = blockIdx.x * 256 + threadIdx.x;
    int s = blockIdx.y;
    h[(long)s * D + d] = E[(long)ids[s] * D + d] * 45.25483399593904f; // sqrt(2048)
}

__global__ void rope_table_kernel(float* __restrict__ c, float* __restrict__ sn) {
    int i = threadIdx.x;   // 0..127
    int p = blockIdx.x;    // 0..S-1
    float inv = powf(10000.f, -(float)i / 128.f);
    float a = (float)p * inv;
    c[p * 128 + i] = cosf(a);
    sn[p * 128 + i] = sinf(a);
}

// fp32 -> bf16 conversion (grid-stride, 8 elems/thread/iter)
__global__ void cvt_bf16_kernel(const float* __restrict__ src, __hip_bfloat16* __restrict__ dst,
                                long n8) {
    long stride = (long)gridDim.x * 256;
    for (long i = (long)blockIdx.x * 256 + threadIdx.x; i < n8; i += stride) {
        long o = i * 8;
        float4 a = *(const float4*)(src + o);
        float4 b = *(const float4*)(src + o + 4);
        __hip_bfloat16 h8[8] = {
            __float2bfloat16(a.x), __float2bfloat16(a.y),
            __float2bfloat16(a.z), __float2bfloat16(a.w),
            __float2bfloat16(b.x), __float2bfloat16(b.y),
            __float2bfloat16(b.z), __float2bfloat16(b.w)};
        *(uint4*)(dst + o) = *(const uint4*)h8;
    }
}

// fp32 (rows x 2048) -> bf16 at interleaved rows: dst row = 2*row + half
__global__ void cvt_inter_kernel(const float* __restrict__ src, __hip_bfloat16* __restrict__ dst,
                                 int half, long n8) {
    long stride = (long)gridDim.x * 256;
    for (long i = (long)blockIdx.x * 256 + threadIdx.x; i < n8; i += stride) {
        long o = i * 8;
        long row = o >> 11, col = o & 2047;
        float4 a = *(const float4*)(src + o);
        float4 b = *(const float4*)(src + o + 4);
        __hip_bfloat16 h8[8] = {
            __float2bfloat16(a.x), __float2bfloat16(a.y),
            __float2bfloat16(a.z), __float2bfloat16(a.w),
            __float2bfloat16(b.x), __float2bfloat16(b.y),
            __float2bfloat16(b.z), __float2bfloat16(b.w)};
        *(uint4*)(dst + ((row * 2 + half) << 11) + col) = *(const uint4*)h8;
    }
}

// x = rms(h, w) -> bf16
__global__ void rms_bf16_kernel(const float* __restrict__ h, const float* __restrict__ w,
                                __hip_bfloat16* __restrict__ o) {
    int s = blockIdx.x;
    const float* row = h + (long)s * D;
    float vals[8], ss = 0.f;
    #pragma unroll
    for (int t = 0; t < 8; ++t) {
        int j = t * 256 + threadIdx.x;
        float v = row[j]; vals[t] = v; ss += v * v;
    }
    ss = blk_sum(ss);
    float r = rsqrtf(ss * (1.f / D) + 1e-6f);
    #pragma unroll
    for (int t = 0; t < 8; ++t) {
        int j = t * 256 + threadIdx.x;
        o[(long)s * D + j] = __float2bfloat16(vals[t] * r * (1.f + w[j]));
    }
}

// h += rms(t, w)
__global__ void resid_rms_kernel(float* __restrict__ h, const float* __restrict__ tt,
                                 const float* __restrict__ w) {
    int s = blockIdx.x;
    const float* row = tt + (long)s * D;
    float* hr = h + (long)s * D;
    float vals[8], ss = 0.f;
    #pragma unroll
    for (int t = 0; t < 8; ++t) {
        int j = t * 256 + threadIdx.x;
        float v = row[j]; vals[t] = v; ss += v * v;
    }
    ss = blk_sum(ss);
    float r = rsqrtf(ss * (1.f / D) + 1e-6f);
    #pragma unroll
    for (int t = 0; t < 8; ++t) {
        int j = t * 256 + threadIdx.x;
        hr[j] += vals[t] * r * (1.f + w[j]);
    }
}

// in-place RoPE on rows with stride ldx; head offset hh*HD; 128 threads per (s, head)
__global__ void rope_kernel(__hip_bfloat16* __restrict__ x, const float* __restrict__ cb,
                            const float* __restrict__ sb, int ldx) {
    int s = blockIdx.x, hh = blockIdx.y, i = threadIdx.x; // i in 0..127
    __hip_bfloat16* p = x + (long)s * ldx + hh * HD;
    float x1 = __bfloat162float(p[i]);
    float x2 = __bfloat162float(p[128 + i]);
    float c = cb[s * 128 + i], sn = sb[s * 128 + i];
    p[i]       = __float2bfloat16(x1 * c - x2 * sn);
    p[128 + i] = __float2bfloat16(x1 * sn + x2 * c);
}

// v rows (stride ldv) -> vT (NKV, HD, S) bf16
__global__ void transpose_v_kernel(const __hip_bfloat16* __restrict__ v,
                                   __hip_bfloat16* __restrict__ vt, int ldv) {
    __shared__ ushort tile[64][65];
    int s0 = blockIdx.x * 64, d0 = blockIdx.y * 64, kv = blockIdx.z;
    const ushort* vin = (const ushort*)v;
    ushort* vout = (ushort*)vt;
    #pragma unroll
    for (int it = 0; it < 4; ++it) {
        int slot = it * 256 + threadIdx.x;
        int r = slot >> 4, c4 = (slot & 15) << 2;
        ushort4 x = *(const ushort4*)(vin + (long)(s0 + r) * ldv + kv * HD + d0 + c4);
        tile[r][c4] = x.x; tile[r][c4 + 1] = x.y; tile[r][c4 + 2] = x.z; tile[r][c4 + 3] = x.w;
    }
    __syncthreads();
    #pragma unroll
    for (int it = 0; it < 4; ++it) {
        int slot = it * 256 + threadIdx.x;
        int rr = slot >> 4, c4 = (slot & 15) << 2;
        ushort4 y;
        y.x = tile[c4][rr]; y.y = tile[c4 + 1][rr]; y.z = tile[c4 + 2][rr]; y.w = tile[c4 + 3][rr];
        *(ushort4*)(vout + (long)kv * HD * S + (long)(d0 + rr) * S + s0 + c4) = y;
    }
}

// scores (NH,S,S) bf16 -> probs bf16, with scale, tanh softcap, mask, softmax.
__global__ void softmax_kernel(const __hip_bfloat16* __restrict__ sc,
                               __hip_bfloat16* __restrict__ pr, int isLocal) {
    int i = blockIdx.x, hh = blockIdx.y;
    const __hip_bfloat16* row = sc + ((long)hh * S + i) * S;
    __hip_bfloat16* orow = pr + ((long)hh * S + i) * S;
    int lo = isLocal ? max(0, i - (WINDOW - 1)) : 0;
    float vals[8];
    float m = -3.0e38f;
    #pragma unroll
    for (int t = 0; t < 8; ++t) {
        int j = t * 256 + threadIdx.x;
        bool chunkAny = (t * 256 <= i) && (t * 256 + 255 >= lo);
        if (chunkAny) {
            bool valid = (j <= i) && (j >= lo);
            float v = tanhf(__bfloat162float(row[j]) * (0.0625f / 50.f)) * 50.f;
            vals[t] = valid ? v : -3.0e38f;
            m = fmaxf(m, vals[t]);
        } else {
            vals[t] = -3.0e38f;
        }
    }
    m = blk_max(m);
    float ps[8], ssum = 0.f;
    #pragma unroll
    for (int t = 0; t < 8; ++t) {
        float p = (vals[t] > -1.0e38f) ? __expf(vals[t] - m) : 0.f;
        ps[t] = p; ssum += p;
    }
    ssum = blk_sum(ssum);
    float inv = 1.f / ssum;
    #pragma unroll
    for (int t = 0; t < 8; ++t) {
        int j = t * 256 + threadIdx.x;
        orow[j] = __float2bfloat16(ps[t] * inv);
    }
}

// gate half *= up half, packed gu[S][16384] (fallback path only)
__global__ void mul_gu_kernel(__hip_bfloat16* __restrict__ gu) {
    long idx = ((long)blockIdx.x * 256 + threadIdx.x) * 8;
    long s = idx >> 13;
    long f = idx & 8191;
    __hip_bfloat16* gp = gu + s * 16384 + f;
    const __hip_bfloat16* up = gu + s * 16384 + 8192 + f;
    uint4 gv = *(const uint4*)gp;
    uint4 uv = *(const uint4*)up;
    const __hip_bfloat16* gb = (const __hip_bfloat16*)&gv;
    const __hip_bfloat16* ub = (const __hip_bfloat16*)&uv;
    __hip_bfloat16 o[8];
    #pragma unroll
    for (int j = 0; j < 8; ++j)
        o[j] = __float2bfloat16(__bfloat162float(gb[j]) * __bfloat162float(ub[j]));
    *(uint4*)gp = *(const uint4*)o;
}

// ---------------- generic pipelined GEMM: C[M,N] = A[M,K] * B[N,K]^T, bf16 ----------------
// Tile BM=WM*MI*16 x BN=WN*NI*16, BK=32, threads T=WM*WN*64 (BM==BN==T/2 required by staging).
// 4 LDS buffers (64 KiB at 128^2 -> 2 blocks/CU), depth-3 prefetch, 2 sub-phases/K-tile,
// counted vmcnt(8), setprio around MFMA, both-sides XOR swizzle, XCD-chunked 1-D grid remap
// (nwg % 8 == 0).
// EPI: 0=f32, 1=bf16, 3=tanh(x/30)*30->f32 (LM head),
//      5=interleaved gelu(gate)*up -> bf16 (B rows interleaved wg/wu; even lanes write f=col/2)
// kMode: 0 none; 1 causal score-tile skip; 2 local score-tile skip; 3 causal PV K-range; 4 local PV K-range
template<int EPI, int WM, int WN, int MI, int NI>
__global__ __launch_bounds__(WM*WN*64, 2) void gemm_pipe(
    const __hip_bfloat16* __restrict__ A, const __hip_bfloat16* __restrict__ B,
    void* __restrict__ Cv, int K, int lda, int ldb, int ldc,
    long aBatch, long bBatch, long cBatch, int bzDiv, int gx, int kMode) {
    constexpr int T  = WM * WN * 64;
    constexpr int BM = WM * MI * 16;
    constexpr int BN = WN * NI * 16;
    constexpr int AE = BM * 32;
    constexpr int BE = BN * 32;
    __shared__ __hip_bfloat16 lds[4][AE + BE];

    const int tid = threadIdx.x;
    const int nwg = gridDim.x;
    const int orig = blockIdx.x;
    const int wgid = (orig & 7) * (nwg >> 3) + (orig >> 3);
    const int bx = wgid % gx, by = wgid / gx;
    const int bz = blockIdx.z;

    int kstart = 0, kend = K;
    if (kMode == 1) { if (by > bx) return; }
    else if (kMode == 2) { if (by > bx || bx - by >= 9) return; }
    else if (kMode == 3) { kend = min(K, (bx + 1) * BM); }
    else if (kMode == 4) { kend = min(K, (bx + 1) * BM); kstart = max(0, (bx - 1024 / BM) * BM); }

    const __hip_bfloat16* Ab = A + (long)bz * aBatch + (long)bx * BM * lda;
    const __hip_bfloat16* Bb = B + (long)(bz / bzDiv) * bBatch + (long)by * BN * ldb;

    const int w = tid >> 6, l = tid & 63;
    const int wm = w / WN, wn = w % WN;
    const int wrow = wm * MI * 16, wcol = wn * NI * 16;
    const int fr = l & 15, g = l >> 4;
    const int sR = tid >> 2;
    const int sc = tid & 3;

    floatx4 acc[MI][NI] = {};
    bf16x8 bfv[NI];
    bf16x8 af[MI / 2];

    auto stageA = [&](int t, int buf) {
        const int k0 = kstart + t * 32;
        #pragma unroll
        for (int i = 0; i < 2; ++i) {
            int row = sR + i * (T / 4);
            int scol = ((sc ^ ((row >> 1) & 3)) << 3);
            __builtin_amdgcn_global_load_lds(
                (kGlb*)(Ab + (long)row * lda + k0 + scol),
                (kLds*)(&lds[buf][0] + tid * 8 + i * (T * 8)), 16, 0, 0);
        }
    };
    auto stageB = [&](int t, int buf) {
        const int k0 = kstart + t * 32;
        #pragma unroll
        for (int i = 0; i < 2; ++i) {
            int row = sR + i * (T / 4);
            int scol = ((sc ^ ((row >> 1) & 3)) << 3);
            __builtin_amdgcn_global_load_lds(
                (kGlb*)(Bb + (long)row * ldb + k0 + scol),
                (kLds*)(&lds[buf][AE] + tid * 8 + i * (T * 8)), 16, 0, 0);
        }
    };

    auto phase0 = [&](int buf, int t3, bool doStage) {
        const char* AsB = (const char*)&lds[buf][0];
        const char* BsB = (const char*)&lds[buf][AE];
        #pragma unroll
        for (int mi = 0; mi < MI / 2; ++mi) {
            int ra = wrow + mi * 16 + fr;
            af[mi] = *(const bf16x8*)(AsB + ra * 64 + ((g ^ ((ra >> 1) & 3)) << 4));
        }
        #pragma unroll
        for (int ni = 0; ni < NI; ++ni) {
            int rb = wcol + ni * 16 + fr;
            bfv[ni] = *(const bf16x8*)(BsB + rb * 64 + ((g ^ ((rb >> 1) & 3)) << 4));
        }
        if (doStage) stageA(t3, t3 & 3);
        __builtin_amdgcn_s_barrier();
        asm volatile("s_waitcnt lgkmcnt(0)" ::: "memory");
        __builtin_amdgcn_sched_barrier(0);
        __builtin_amdgcn_s_setprio(1);
        #pragma unroll
        for (int mi = 0; mi < MI / 2; ++mi)
            #pragma unroll
            for (int ni = 0; ni < NI; ++ni)
                acc[mi][ni] = __builtin_amdgcn_mfma_f32_16x16x32_bf16(af[mi], bfv[ni], acc[mi][ni], 0, 0, 0);
        __builtin_amdgcn_s_setprio(0);
        __builtin_amdgcn_sched_barrier(0);
        __builtin_amdgcn_s_barrier();
    };

    auto phase1 = [&](int buf, int t3, bool doStage, int vm) {
        const char* AsB = (const char*)&lds[buf][0];
        #pragma unroll
        for (int mi = 0; mi < MI / 2; ++mi) {
            int ra = wrow + (MI / 2 + mi) * 16 + fr;
            af[mi] = *(const bf16x8*)(AsB + ra * 64 + ((g ^ ((ra >> 1) & 3)) << 4));
        }
        if (doStage) stageB(t3, t3 & 3);
        if (vm == 8)      asm volatile("s_waitcnt vmcnt(8)" ::: "memory");
        else if (vm == 4) asm volatile("s_waitcnt vmcnt(4)" ::: "memory");
        else if (vm == 0) asm volatile("s_waitcnt vmcnt(0)" ::: "memory");
        __builtin_amdgcn_s_barrier();
        asm volatile("s_waitcnt lgkmcnt(0)" ::: "memory");
        __builtin_amdgcn_sched_barrier(0);
        __builtin_amdgcn_s_setprio(1);
        #pragma unroll
        for (int mi = 0; mi < MI / 2; ++mi)
            #pragma unroll
            for (int ni = 0; ni < NI; ++ni)
                acc[MI / 2 + mi][ni] = __builtin_amdgcn_mfma_f32_16x16x32_bf16(af[mi], bfv[ni], acc[MI / 2 + mi][ni], 0, 0, 0);
        __builtin_amdgcn_s_setprio(0);
        __builtin_amdgcn_sched_barrier(0);
        __builtin_amdgcn_s_barrier();
    };

    const int nt = (kend - kstart) >> 5;
    stageA(0, 0); stageB(0, 0);
    stageA(1, 1); stageB(1, 1);
    stageA(2, 2); stageB(2, 2);
    asm volatile("s_waitcnt vmcnt(8)" ::: "memory");
    __builtin_amdgcn_s_barrier();

    for (int t = 0; t < nt - 3; ++t) {
        const int b = t & 3;
        phase0(b, t + 3, true);
        phase1(b, t + 3, true, 8);
    }
    phase0((nt - 3) & 3, 0, false); phase1((nt - 3) & 3, 0, false, 4);
    phase0((nt - 2) & 3, 0, false); phase1((nt - 2) & 3, 0, false, 0);
    phase0((nt - 1) & 3, 0, false); phase1((nt - 1) & 3, 0, false, -1);

    const long cBase = (long)bz * cBatch + (long)bx * BM * ldc + (long)by * BN;
    const int rg = (l >> 4) * 4;
    #pragma unroll
    for (int mi = 0; mi < MI; ++mi) {
        #pragma unroll
        for (int ni = 0; ni < NI; ++ni) {
            #pragma unroll
            for (int r = 0; r < 4; ++r) {
                int row = wrow + mi * 16 + rg + r;
                int col = wcol + ni * 16 + fr;
                float v = acc[mi][ni][r];
                if constexpr (EPI == 5) {
                    // B rows interleaved: even col = gate (wg), odd col = up (wu).
                    float pv = __shfl_xor(v, 1);   // partner lane: same row, col^1
                    if (!(fr & 1)) {
                        float gg = 0.5f * v * (1.f + tanhf(0.7978845608f * (v + 0.044715f * v * v * v)));
                        long idx5 = ((long)bx * BM + row) * (long)ldc + (long)by * (BN / 2) + (col >> 1);
                        ((__hip_bfloat16*)Cv)[idx5] = __float2bfloat16(gg * pv);
                    }
                } else {
                    long idx = cBase + (long)row * ldc + col;
                    if constexpr (EPI == 0) {
                        ((float*)Cv)[idx] = v;
                    } else if constexpr (EPI == 1) {
                        ((__hip_bfloat16*)Cv)[idx] = __float2bfloat16(v);
                    } else if constexpr (EPI == 3) {
                        ((float*)Cv)[idx] = tanhf(v * (1.f / 30.f)) * 30.f;
                    }
                }
            }
        }
    }
}

// ---------------- fallback GEMM with fp32 B staging (used only if ws too small) ----------------
template<int EPI>
__global__ __launch_bounds__(256) void gemm_f32w(
    const __hip_bfloat16* __restrict__ A, const float* __restrict__ Bv,
    void* __restrict__ Cv, int K, int lda, int ldb, int ldc) {
    __shared__ __hip_bfloat16 As[128][32];
    __shared__ __hip_bfloat16 Bs[128][32];
    const int tid = threadIdx.x;
    const __hip_bfloat16* Ab = A + (long)blockIdx.x * 128 * lda;
    const float* Bb = Bv + (long)blockIdx.y * 128 * ldb;
    const int wid = tid >> 6, lane = tid & 63;
    const int wr = (wid >> 1) * 64, wc = (wid & 1) * 64;
    const int fr = lane & 15;
    const int kb = (lane >> 4) * 8;
    floatx4 acc[4][4] = {};
    for (int k0 = 0; k0 < K; k0 += 32) {
        __syncthreads();
        #pragma unroll
        for (int it = 0; it < 2; ++it) {
            int slot = tid + it * 256;
            int r = slot >> 2, c8 = (slot & 3) * 8;
            *reinterpret_cast<uint4*>(&As[r][c8]) =
                *reinterpret_cast<const uint4*>(Ab + (long)r * lda + k0 + c8);
        }
        #pragma unroll
        for (int it = 0; it < 4; ++it) {
            int slot = tid + it * 256;
            int r = slot >> 3, c4 = (slot & 7) * 4;
            float4 f = *reinterpret_cast<const float4*>(Bb + (long)r * ldb + k0 + c4);
            __hip_bfloat16 t4[4] = {__float2bfloat16(f.x), __float2bfloat16(f.y),
                                    __float2bfloat16(f.z), __float2bfloat16(f.w)};
            *reinterpret_cast<ushort4*>(&Bs[r][c4]) = *reinterpret_cast<const ushort4*>(t4);
        }
        __syncthreads();
        bf16x8 af[4], bfr[4];
        #pragma unroll
        for (int i = 0; i < 4; ++i)
            af[i] = *reinterpret_cast<const bf16x8*>(&As[wr + i * 16 + fr][kb]);
        #pragma unroll
        for (int j = 0; j < 4; ++j)
            bfr[j] = *reinterpret_cast<const bf16x8*>(&Bs[wc + j * 16 + fr][kb]);
        #pragma unroll
        for (int i = 0; i < 4; ++i)
            #pragma unroll
            for (int j = 0; j < 4; ++j)
                acc[i][j] = __builtin_amdgcn_mfma_f32_16x16x32_bf16(af[i], bfr[j], acc[i][j], 0, 0, 0);
    }
    const long cTile = (long)blockIdx.x * 128 * ldc + (long)blockIdx.y * 128;
    const int rg = (lane >> 4) * 4;
    #pragma unroll
    for (int i = 0; i < 4; ++i)
        #pragma unroll
        for (int j = 0; j < 4; ++j)
            #pragma unroll
            for (int r = 0; r < 4; ++r) {
                int row = wr + i * 16 + rg + r;
                int col = wc + j * 16 + fr;
                long idx = cTile + (long)row * ldc + col;
                float v = acc[i][j][r];
                if constexpr (EPI == 0) ((float*)Cv)[idx] = v;
                else if constexpr (EPI == 1) ((__hip_bfloat16*)Cv)[idx] = __float2bfloat16(v);
                else if constexpr (EPI == 2) {
                    float gg = 0.5f * v * (1.f + tanhf(0.7978845608f * (v + 0.044715f * v * v * v)));
                    ((__hip_bfloat16*)Cv)[idx] = __float2bfloat16(gg);
                } else ((float*)Cv)[idx] = tanhf(v * (1.f / 30.f)) * 30.f;
            }
}

// ---------------- host ----------------
extern "C" void kernel_launch(void* const* d_in, const int* in_sizes, int n_in,
                              void* d_out, int out_size, void* d_ws, size_t ws_size,
                              hipStream_t stream) {
    const int*   ids    = (const int*)d_in[0];
    const float* embedW = (const float*)d_in[1];
    const float* wq     = (const float*)d_in[2];
    const float* wk     = (const float*)d_in[3];
    const float* wv     = (const float*)d_in[4];
    const float* wo     = (const float*)d_in[5];
    const float* wg     = (const float*)d_in[6];
    const float* wu     = (const float*)d_in[7];
    const float* wd     = (const float*)d_in[8];
    const float* ln_in  = (const float*)d_in[9];
    const float* ln_pa  = (const float*)d_in[10];
    const float* ln_pf  = (const float*)d_in[11];
    const float* ln_pff = (const float*)d_in[12];
    const float* ln_f   = (const float*)d_in[13];
    const float* w_lm   = (const float*)d_in[14];
    float* out = (float*)d_out;

    char* ws = (char*)d_ws;
    size_t off = 0;
    auto alloc = [&](size_t bytes) -> void* {
        size_t o = (off + 255) & ~(size_t)255;
        off = o + bytes;
        return (void*)(ws + o);
    };

    float* h            = (float*)alloc((size_t)S * D * 4);
    __hip_bfloat16* xb  = (__hip_bfloat16*)alloc((size_t)S * D * 2);
    __hip_bfloat16* qkvb = (__hip_bfloat16*)alloc((size_t)S * 4096 * 2); // q|k|v packed
    __hip_bfloat16* vT  = (__hip_bfloat16*)alloc((size_t)NKV * HD * S * 2);
    __hip_bfloat16* ab  = (__hip_bfloat16*)alloc((size_t)S * NH * HD * 2);
    float* tmpf         = (float*)alloc((size_t)S * D * 4);
    __hip_bfloat16* guP = (__hip_bfloat16*)alloc((size_t)S * FF * 2);    // gelu(gate)*up
    __hip_bfloat16* gu  = (__hip_bfloat16*)alloc((size_t)S * 16384 * 2); // fallback only
    float* cosb         = (float*)alloc((size_t)S * 128 * 4);
    float* sinb         = (float*)alloc((size_t)S * 128 * 4);
    __hip_bfloat16* scores = (__hip_bfloat16*)alloc((size_t)NH * S * S * 2);
    __hip_bfloat16* probs  = (__hip_bfloat16*)alloc((size_t)NH * S * S * 2);

    const long SLq = 2048L * 2048, SLkv = 1024L * 2048, SLff = 8192L * 2048;
    const long nWlm = (long)VOCAB * D;
    __hip_bfloat16* wqkvb = (__hip_bfloat16*)alloc(4L * 4096 * 2048 * 2);
    __hip_bfloat16* wgub  = (__hip_bfloat16*)alloc(4L * 16384 * 2048 * 2); // interleaved wg/wu
    __hip_bfloat16* wob   = (__hip_bfloat16*)alloc(4L * SLq * 2);
    __hip_bfloat16* wdb   = (__hip_bfloat16*)alloc(4L * SLff * 2);
    __hip_bfloat16* wlmb  = (__hip_bfloat16*)alloc(nWlm * 2);
    const bool big = (off <= ws_size);
    (void)in_sizes; (void)n_in; (void)out_size;

    rope_table_kernel<<<dim3(S), dim3(128), 0, stream>>>(cosb, sinb);
    embed_kernel<<<dim3(D / 256, S), dim3(256), 0, stream>>>(ids, embedW, h);

    auto cvt = [&](const float* s, __hip_bfloat16* dp, long n) {
        long n8 = n / 8;
        long want = (n8 + 255) / 256;
        int blocks = (int)(want < 2048 ? want : 2048);
        cvt_bf16_kernel<<<dim3(blocks), dim3(256), 0, stream>>>(s, dp, n8);
    };
    auto cvtI = [&](const float* s, __hip_bfloat16* dp, int half, long n) {
        long n8 = n / 8;
        long want = (n8 + 255) / 256;
        int blocks = (int)(want < 2048 ? want : 2048);
        cvt_inter_kernel<<<dim3(blocks), dim3(256), 0, stream>>>(s, dp, half, n8);
    };
    if (big) {
        // LM-head weights converted up-front (converting just before the LM GEMM raised its
        // HBM fetch by ~70 MB in round 9 — fresh dirty L2/L3 collided with the GEMM's reads).
        cvt(w_lm, wlmb, nWlm);
    }

    // p128 launcher: 128x128 2-phase pipeline (256 thr, 64 KiB LDS -> 2 blocks/CU)
    auto p128 = [&](int epi, const __hip_bfloat16* A, const __hip_bfloat16* B, void* C,
                    int K, int lda, int ldb, int ldc, int gx, int gy, int gz,
                    long aB, long bB, long cB, int bzDiv, int kMode) {
        dim3 grid(gx * gy, 1, gz);
        switch (epi) {
        case 0: gemm_pipe<0, 2, 2, 4, 4><<<grid, 256, 0, stream>>>(A, B, C, K, lda, ldb, ldc, aB, bB, cB, bzDiv, gx, kMode); break;
        case 3: gemm_pipe<3, 2, 2, 4, 4><<<grid, 256, 0, stream>>>(A, B, C, K, lda, ldb, ldc, aB, bB, cB, bzDiv, gx, kMode); break;
        case 5: gemm_pipe<5, 2, 2, 4, 4><<<grid, 256, 0, stream>>>(A, B, C, K, lda, ldb, ldc, aB, bB, cB, bzDiv, gx, kMode); break;
        default: gemm_pipe<1, 2, 2, 4, 4><<<grid, 256, 0, stream>>>(A, B, C, K, lda, ldb, ldc, aB, bB, cB, bzDiv, gx, kMode); break;
        }
    };

    for (int l = 0; l < NLAYER; ++l) {
        int isLocal = (l % 2 == 0) ? 1 : 0;
        rms_bf16_kernel<<<dim3(S), dim3(256), 0, stream>>>(h, ln_in + l * D, xb);
        if (big) {
            // convert this layer's qkv weights just-in-time (L3-hot for the GEMM read)
            cvt(wq + l * SLq,  wqkvb + (size_t)l * 4096 * 2048,                SLq);
            cvt(wk + l * SLkv, wqkvb + (size_t)l * 4096 * 2048 + 2048L * 2048, SLkv);
            cvt(wv + l * SLkv, wqkvb + (size_t)l * 4096 * 2048 + 3072L * 2048, SLkv);
            p128(1, xb, wqkvb + (size_t)l * 4096 * 2048, qkvb, D, D, D, 4096, 16, 32, 1, 0, 0, 0, 1, 0);
        } else {
            gemm_f32w<1><<<dim3(16, 16), 256, 0, stream>>>(xb, wq + l * SLq, qkvb, D, D, D, 4096);
            gemm_f32w<1><<<dim3(16, 8), 256, 0, stream>>>(xb, wk + l * SLkv, qkvb + 2048, D, D, D, 4096);
            gemm_f32w<1><<<dim3(16, 8), 256, 0, stream>>>(xb, wv + l * SLkv, qkvb + 3072, D, D, D, 4096);
        }
        rope_kernel<<<dim3(S, NH), dim3(128), 0, stream>>>(qkvb, cosb, sinb, 4096);
        rope_kernel<<<dim3(S, NKV), dim3(128), 0, stream>>>(qkvb + 2048, cosb, sinb, 4096);
        transpose_v_kernel<<<dim3(S / 64, HD / 64, NKV), 256, 0, stream>>>(qkvb + 3072, vT, 4096);
        // scores = q @ k^T per head (bf16 out), masked-tile skip
        p128(1, qkvb, qkvb + 2048, scores, HD, 4096, 4096, S, 16, 16, NH,
             (long)HD, (long)HD, (long)S * S, 2, isLocal ? 2 : 1);
        softmax_kernel<<<dim3(S, NH), dim3(256), 0, stream>>>(scores, probs, isLocal);
        // a = probs @ vT, K-range restricted to valid band
        p128(1, probs, vT, ab, S, S, S, NH * HD, 16, 2, NH,
             (long)S * S, (long)HD * S, (long)HD, 2, isLocal ? 4 : 3);
        if (big) {
            cvt(wo + l * SLq, wob + (size_t)l * SLq, SLq);
            p128(0, ab, wob + (size_t)l * SLq, tmpf, NH * HD, NH * HD, NH * HD, D, 16, 16, 1, 0, 0, 0, 1, 0);
        } else {
            gemm_f32w<0><<<dim3(16, 16), 256, 0, stream>>>(ab, wo + l * SLq, tmpf, NH * HD, NH * HD, NH * HD, D);
        }
        resid_rms_kernel<<<dim3(S), dim3(256), 0, stream>>>(h, tmpf, ln_pa + l * D);
        rms_bf16_kernel<<<dim3(S), dim3(256), 0, stream>>>(h, ln_pf + l * D, xb);
        if (big) {
            cvtI(wg + l * SLff, wgub + (size_t)l * 16384 * 2048, 0, SLff);
            cvtI(wu + l * SLff, wgub + (size_t)l * 16384 * 2048, 1, SLff);
            // fused gate|up (interleaved rows); 128^2 pipeline, 2048 blocks, 2/CU.
            // epilogue writes gelu(gate)*up -> guP [S][8192]
            p128(5, xb, wgub + (size_t)l * 16384 * 2048, guP, D, D, D, FF, 16, 128, 1, 0, 0, 0, 1, 0);
        } else {
            gemm_f32w<2><<<dim3(16, 64), 256, 0, stream>>>(xb, wg + l * SLff, gu, D, D, D, 16384);
            gemm_f32w<1><<<dim3(16, 64), 256, 0, stream>>>(xb, wu + l * SLff, gu + 8192, D, D, D, 16384);
            mul_gu_kernel<<<dim3((S * FF) / (256 * 8)), 256, 0, stream>>>(gu);
        }
        if (big) {
            cvt(wd + l * SLff, wdb + (size_t)l * SLff, SLff);
            p128(0, guP, wdb + (size_t)l * SLff, tmpf, FF, FF, FF, D, 16, 16, 1, 0, 0, 0, 1, 0);
        } else {
            gemm_f32w<0><<<dim3(16, 16), 256, 0, stream>>>(gu, wd + l * SLff, tmpf, FF, 16384, FF, D);
        }
        resid_rms_kernel<<<dim3(S), dim3(256), 0, stream>>>(h, tmpf, ln_pff + l * D);
    }

    rms_bf16_kernel<<<dim3(S), dim3(256), 0, stream>>>(h, ln_f, xb);
    if (big) {
        // LM head: 128^2 pipeline, 16 x 250 = 4000 blocks (%8==0), tanh(x/30)*30 -> f32
        p128(3, xb, wlmb, out, D, D, D, VOCAB, 16, 250, 1, 0, 0, 0, 1, 0);
    } else {
        gemm_f32w<3><<<dim3(16, VOCAB / 128), 256, 0, stream>>>(xb, w_lm, out, D, D, D, VOCAB);
    }
}

// Round 11
// 2525.382 us; speedup vs baseline: 1.0714x; 1.0714x over previous
//
#include <hip/hip_runtime.h>
#include <hip/hip_bf16.h>

typedef __attribute__((ext_vector_type(8))) __bf16 bf16x8;
typedef __attribute__((ext_vector_type(4))) float floatx4;

typedef __attribute__((address_space(1))) const unsigned char kGlb;
typedef __attribute__((address_space(3))) unsigned char kLds;

static constexpr int S = 2048;
static constexpr int D = 2048;
static constexpr int HD = 256;
static constexpr int NH = 8;
static constexpr int NKV = 4;
static constexpr int NLAYER = 4;
static constexpr int VOCAB = 32000;
static constexpr int FF = 8192;
static constexpr int WINDOW = 1024;

// ---------------- block reduction helpers (256 threads = 4 waves) ----------------
__device__ __forceinline__ float blk_sum(float v) {
    __shared__ float sm[4];
    #pragma unroll
    for (int o = 32; o > 0; o >>= 1) v += __shfl_down(v, o, 64);
    int lane = threadIdx.x & 63, w = threadIdx.x >> 6;
    __syncthreads();
    if (lane == 0) sm[w] = v;
    __syncthreads();
    return sm[0] + sm[1] + sm[2] + sm[3];
}

__device__ __forceinline__ float blk_max(float v) {
    __shared__ float sm[4];
    #pragma unroll
    for (int o = 32; o > 0; o >>= 1) v = fmaxf(v, __shfl_down(v, o, 64));
    int lane = threadIdx.x & 63, w = threadIdx.x >> 6;
    __syncthreads();
    if (lane == 0) sm[w] = v;
    __syncthreads();
    return fmaxf(fmaxf(sm[0], sm[1]), fmaxf(sm[2], sm[3]));
}

// ---------------- elementwise kernels ----------------
__global__ void embed_kernel(const int* __restrict__ ids, const float* __restrict__ E,
                             float* __restrict__ h) {
    int d = blockIdx.x * 256 + threadIdx.x;
    int s = blockIdx.y;
    h[(long)s * D + d] = E[(long)ids[s] * D + d] * 45.25483399593904f; // sqrt(2048)
}

__global__ void rope_table_kernel(float* __restrict__ c, float* __restrict__ sn) {
    int i = threadIdx.x;   // 0..127
    int p = blockIdx.x;    // 0..S-1
    float inv = powf(10000.f, -(float)i / 128.f);
    float a = (float)p * inv;
    c[p * 128 + i] = cosf(a);
    sn[p * 128 + i] = sinf(a);
}

// fp32 -> bf16 conversion (grid-stride, 8 elems/thread/iter)
__global__ void cvt_bf16_kernel(const float* __restrict__ src, __hip_bfloat16* __restrict__ dst,
                                long n8) {
    long stride = (long)gridDim.x * 256;
    for (long i = (long)blockIdx.x * 256 + threadIdx.x; i < n8; i += stride) {
        long o = i * 8;
        float4 a = *(const float4*)(src + o);
        float4 b = *(const float4*)(src + o + 4);
        __hip_bfloat16 h8[8] = {
            __float2bfloat16(a.x), __float2bfloat16(a.y),
            __float2bfloat16(a.z), __float2bfloat16(a.w),
            __float2bfloat16(b.x), __float2bfloat16(b.y),
            __float2bfloat16(b.z), __float2bfloat16(b.w)};
        *(uint4*)(dst + o) = *(const uint4*)h8;
    }
}

// fp32 (rows x 2048) -> bf16 at interleaved rows: dst row = 2*row + half
__global__ void cvt_inter_kernel(const float* __restrict__ src, __hip_bfloat16* __restrict__ dst,
                                 int half, long n8) {
    long stride = (long)gridDim.x * 256;
    for (long i = (long)blockIdx.x * 256 + threadIdx.x; i < n8; i += stride) {
        long o = i * 8;
        long row = o >> 11, col = o & 2047;
        float4 a = *(const float4*)(src + o);
        float4 b = *(const float4*)(src + o + 4);
        __hip_bfloat16 h8[8] = {
            __float2bfloat16(a.x), __float2bfloat16(a.y),
            __float2bfloat16(a.z), __float2bfloat16(a.w),
            __float2bfloat16(b.x), __float2bfloat16(b.y),
            __float2bfloat16(b.z), __float2bfloat16(b.w)};
        *(uint4*)(dst + ((row * 2 + half) << 11) + col) = *(const uint4*)h8;
    }
}

// x = rms(h, w) -> bf16
__global__ void rms_bf16_kernel(const float* __restrict__ h, const float* __restrict__ w,
                                __hip_bfloat16* __restrict__ o) {
    int s = blockIdx.x;
    const float* row = h + (long)s * D;
    float vals[8], ss = 0.f;
    #pragma unroll
    for (int t = 0; t < 8; ++t) {
        int j = t * 256 + threadIdx.x;
        float v = row[j]; vals[t] = v; ss += v * v;
    }
    ss = blk_sum(ss);
    float r = rsqrtf(ss * (1.f / D) + 1e-6f);
    #pragma unroll
    for (int t = 0; t < 8; ++t) {
        int j = t * 256 + threadIdx.x;
        o[(long)s * D + j] = __float2bfloat16(vals[t] * r * (1.f + w[j]));
    }
}

// h += rms(t, w)
__global__ void resid_rms_kernel(float* __restrict__ h, const float* __restrict__ tt,
                                 const float* __restrict__ w) {
    int s = blockIdx.x;
    const float* row = tt + (long)s * D;
    float* hr = h + (long)s * D;
    float vals[8], ss = 0.f;
    #pragma unroll
    for (int t = 0; t < 8; ++t) {
        int j = t * 256 + threadIdx.x;
        float v = row[j]; vals[t] = v; ss += v * v;
    }
    ss = blk_sum(ss);
    float r = rsqrtf(ss * (1.f / D) + 1e-6f);
    #pragma unroll
    for (int t = 0; t < 8; ++t) {
        int j = t * 256 + threadIdx.x;
        hr[j] += vals[t] * r * (1.f + w[j]);
    }
}

// in-place RoPE on rows with stride ldx; head offset hh*HD; 128 threads per (s, head)
__global__ void rope_kernel(__hip_bfloat16* __restrict__ x, const float* __restrict__ cb,
                            const float* __restrict__ sb, int ldx) {
    int s = blockIdx.x, hh = blockIdx.y, i = threadIdx.x; // i in 0..127
    __hip_bfloat16* p = x + (long)s * ldx + hh * HD;
    float x1 = __bfloat162float(p[i]);
    float x2 = __bfloat162float(p[128 + i]);
    float c = cb[s * 128 + i], sn = sb[s * 128 + i];
    p[i]       = __float2bfloat16(x1 * c - x2 * sn);
    p[128 + i] = __float2bfloat16(x1 * sn + x2 * c);
}

// v rows (stride ldv) -> vT (NKV, HD, S) bf16
__global__ void transpose_v_kernel(const __hip_bfloat16* __restrict__ v,
                                   __hip_bfloat16* __restrict__ vt, int ldv) {
    __shared__ ushort tile[64][65];
    int s0 = blockIdx.x * 64, d0 = blockIdx.y * 64, kv = blockIdx.z;
    const ushort* vin = (const ushort*)v;
    ushort* vout = (ushort*)vt;
    #pragma unroll
    for (int it = 0; it < 4; ++it) {
        int slot = it * 256 + threadIdx.x;
        int r = slot >> 4, c4 = (slot & 15) << 2;
        ushort4 x = *(const ushort4*)(vin + (long)(s0 + r) * ldv + kv * HD + d0 + c4);
        tile[r][c4] = x.x; tile[r][c4 + 1] = x.y; tile[r][c4 + 2] = x.z; tile[r][c4 + 3] = x.w;
    }
    __syncthreads();
    #pragma unroll
    for (int it = 0; it < 4; ++it) {
        int slot = it * 256 + threadIdx.x;
        int rr = slot >> 4, c4 = (slot & 15) << 2;
        ushort4 y;
        y.x = tile[c4][rr]; y.y = tile[c4 + 1][rr]; y.z = tile[c4 + 2][rr]; y.w = tile[c4 + 3][rr];
        *(ushort4*)(vout + (long)kv * HD * S + (long)(d0 + rr) * S + s0 + c4) = y;
    }
}

// scores (NH,S,S) bf16 -> probs bf16, with scale, tanh softcap, mask, softmax.
__global__ void softmax_kernel(const __hip_bfloat16* __restrict__ sc,
                               __hip_bfloat16* __restrict__ pr, int isLocal) {
    int i = blockIdx.x, hh = blockIdx.y;
    const __hip_bfloat16* row = sc + ((long)hh * S + i) * S;
    __hip_bfloat16* orow = pr + ((long)hh * S + i) * S;
    int lo = isLocal ? max(0, i - (WINDOW - 1)) : 0;
    float vals[8];
    float m = -3.0e38f;
    #pragma unroll
    for (int t = 0; t < 8; ++t) {
        int j = t * 256 + threadIdx.x;
        bool chunkAny = (t * 256 <= i) && (t * 256 + 255 >= lo);
        if (chunkAny) {
            bool valid = (j <= i) && (j >= lo);
            float v = tanhf(__bfloat162float(row[j]) * (0.0625f / 50.f)) * 50.f;
            vals[t] = valid ? v : -3.0e38f;
            m = fmaxf(m, vals[t]);
        } else {
            vals[t] = -3.0e38f;
        }
    }
    m = blk_max(m);
    float ps[8], ssum = 0.f;
    #pragma unroll
    for (int t = 0; t < 8; ++t) {
        float p = (vals[t] > -1.0e38f) ? __expf(vals[t] - m) : 0.f;
        ps[t] = p; ssum += p;
    }
    ssum = blk_sum(ssum);
    float inv = 1.f / ssum;
    #pragma unroll
    for (int t = 0; t < 8; ++t) {
        int j = t * 256 + threadIdx.x;
        orow[j] = __float2bfloat16(ps[t] * inv);
    }
}

// gate half *= up half, packed gu[S][16384] (fallback path only)
__global__ void mul_gu_kernel(__hip_bfloat16* __restrict__ gu) {
    long idx = ((long)blockIdx.x * 256 + threadIdx.x) * 8;
    long s = idx >> 13;
    long f = idx & 8191;
    __hip_bfloat16* gp = gu + s * 16384 + f;
    const __hip_bfloat16* up = gu + s * 16384 + 8192 + f;
    uint4 gv = *(const uint4*)gp;
    uint4 uv = *(const uint4*)up;
    const __hip_bfloat16* gb = (const __hip_bfloat16*)&gv;
    const __hip_bfloat16* ub = (const __hip_bfloat16*)&uv;
    __hip_bfloat16 o[8];
    #pragma unroll
    for (int j = 0; j < 8; ++j)
        o[j] = __float2bfloat16(__bfloat162float(gb[j]) * __bfloat162float(ub[j]));
    *(uint4*)gp = *(const uint4*)o;
}

// ---------------- generic pipelined GEMM: C[M,N] = A[M,K] * B[N,K]^T, bf16 ----------------
// Tile BM=WM*MI*16 x BN=WN*NI*16, BK=32, threads T=WM*WN*64 (BM==BN==T/2 required by staging).
// 4 LDS buffers, depth-3 prefetch, 2 sub-phases/K-tile, counted vmcnt(8), setprio around MFMA,
// both-sides XOR swizzle, XCD-chunked 1-D grid remap (nwg % 8 == 0).
// 128^2 (WM2,WN2,MI4,NI4, 256 thr): activations/attention GEMMs (2 blocks/CU).
// 256^2 (WM2,WN4,MI8,NI4, 512 thr): gate|up + LM head (panel reuse fits L3; 128^2 fetched
//   595 MB vs 214 MB on the LM head in round 10 — B-panel re-reads miss L3 at 128-wide).
// EPI: 0=f32, 1=bf16, 3=tanh(x/30)*30->f32 (LM head),
//      5=interleaved gelu(gate)*up -> bf16 (B rows interleaved wg/wu; even lanes write f=col/2)
// kMode: 0 none; 1 causal score-tile skip; 2 local score-tile skip; 3 causal PV K-range; 4 local PV K-range
template<int EPI, int WM, int WN, int MI, int NI>
__global__ __launch_bounds__(WM*WN*64, 2) void gemm_pipe(
    const __hip_bfloat16* __restrict__ A, const __hip_bfloat16* __restrict__ B,
    void* __restrict__ Cv, int K, int lda, int ldb, int ldc,
    long aBatch, long bBatch, long cBatch, int bzDiv, int gx, int kMode) {
    constexpr int T  = WM * WN * 64;
    constexpr int BM = WM * MI * 16;
    constexpr int BN = WN * NI * 16;
    constexpr int AE = BM * 32;
    constexpr int BE = BN * 32;
    __shared__ __hip_bfloat16 lds[4][AE + BE];

    const int tid = threadIdx.x;
    const int nwg = gridDim.x;
    const int orig = blockIdx.x;
    const int wgid = (orig & 7) * (nwg >> 3) + (orig >> 3);
    const int bx = wgid % gx, by = wgid / gx;
    const int bz = blockIdx.z;

    int kstart = 0, kend = K;
    if (kMode == 1) { if (by > bx) return; }
    else if (kMode == 2) { if (by > bx || bx - by >= 9) return; }
    else if (kMode == 3) { kend = min(K, (bx + 1) * BM); }
    else if (kMode == 4) { kend = min(K, (bx + 1) * BM); kstart = max(0, (bx - 1024 / BM) * BM); }

    const __hip_bfloat16* Ab = A + (long)bz * aBatch + (long)bx * BM * lda;
    const __hip_bfloat16* Bb = B + (long)(bz / bzDiv) * bBatch + (long)by * BN * ldb;

    const int w = tid >> 6, l = tid & 63;
    const int wm = w / WN, wn = w % WN;
    const int wrow = wm * MI * 16, wcol = wn * NI * 16;
    const int fr = l & 15, g = l >> 4;
    const int sR = tid >> 2;
    const int sc = tid & 3;

    floatx4 acc[MI][NI] = {};
    bf16x8 bfv[NI];
    bf16x8 af[MI / 2];

    auto stageA = [&](int t, int buf) {
        const int k0 = kstart + t * 32;
        #pragma unroll
        for (int i = 0; i < 2; ++i) {
            int row = sR + i * (T / 4);
            int scol = ((sc ^ ((row >> 1) & 3)) << 3);
            __builtin_amdgcn_global_load_lds(
                (kGlb*)(Ab + (long)row * lda + k0 + scol),
                (kLds*)(&lds[buf][0] + tid * 8 + i * (T * 8)), 16, 0, 0);
        }
    };
    auto stageB = [&](int t, int buf) {
        const int k0 = kstart + t * 32;
        #pragma unroll
        for (int i = 0; i < 2; ++i) {
            int row = sR + i * (T / 4);
            int scol = ((sc ^ ((row >> 1) & 3)) << 3);
            __builtin_amdgcn_global_load_lds(
                (kGlb*)(Bb + (long)row * ldb + k0 + scol),
                (kLds*)(&lds[buf][AE] + tid * 8 + i * (T * 8)), 16, 0, 0);
        }
    };

    auto phase0 = [&](int buf, int t3, bool doStage) {
        const char* AsB = (const char*)&lds[buf][0];
        const char* BsB = (const char*)&lds[buf][AE];
        #pragma unroll
        for (int mi = 0; mi < MI / 2; ++mi) {
            int ra = wrow + mi * 16 + fr;
            af[mi] = *(const bf16x8*)(AsB + ra * 64 + ((g ^ ((ra >> 1) & 3)) << 4));
        }
        #pragma unroll
        for (int ni = 0; ni < NI; ++ni) {
            int rb = wcol + ni * 16 + fr;
            bfv[ni] = *(const bf16x8*)(BsB + rb * 64 + ((g ^ ((rb >> 1) & 3)) << 4));
        }
        if (doStage) stageA(t3, t3 & 3);
        __builtin_amdgcn_s_barrier();
        asm volatile("s_waitcnt lgkmcnt(0)" ::: "memory");
        __builtin_amdgcn_sched_barrier(0);
        __builtin_amdgcn_s_setprio(1);
        #pragma unroll
        for (int mi = 0; mi < MI / 2; ++mi)
            #pragma unroll
            for (int ni = 0; ni < NI; ++ni)
                acc[mi][ni] = __builtin_amdgcn_mfma_f32_16x16x32_bf16(af[mi], bfv[ni], acc[mi][ni], 0, 0, 0);
        __builtin_amdgcn_s_setprio(0);
        __builtin_amdgcn_sched_barrier(0);
        __builtin_amdgcn_s_barrier();
    };

    auto phase1 = [&](int buf, int t3, bool doStage, int vm) {
        const char* AsB = (const char*)&lds[buf][0];
        #pragma unroll
        for (int mi = 0; mi < MI / 2; ++mi) {
            int ra = wrow + (MI / 2 + mi) * 16 + fr;
            af[mi] = *(const bf16x8*)(AsB + ra * 64 + ((g ^ ((ra >> 1) & 3)) << 4));
        }
        if (doStage) stageB(t3, t3 & 3);
        if (vm == 8)      asm volatile("s_waitcnt vmcnt(8)" ::: "memory");
        else if (vm == 4) asm volatile("s_waitcnt vmcnt(4)" ::: "memory");
        else if (vm == 0) asm volatile("s_waitcnt vmcnt(0)" ::: "memory");
        __builtin_amdgcn_s_barrier();
        asm volatile("s_waitcnt lgkmcnt(0)" ::: "memory");
        __builtin_amdgcn_sched_barrier(0);
        __builtin_amdgcn_s_setprio(1);
        #pragma unroll
        for (int mi = 0; mi < MI / 2; ++mi)
            #pragma unroll
            for (int ni = 0; ni < NI; ++ni)
                acc[MI / 2 + mi][ni] = __builtin_amdgcn_mfma_f32_16x16x32_bf16(af[mi], bfv[ni], acc[MI / 2 + mi][ni], 0, 0, 0);
        __builtin_amdgcn_s_setprio(0);
        __builtin_amdgcn_sched_barrier(0);
        __builtin_amdgcn_s_barrier();
    };

    const int nt = (kend - kstart) >> 5;
    stageA(0, 0); stageB(0, 0);
    stageA(1, 1); stageB(1, 1);
    stageA(2, 2); stageB(2, 2);
    asm volatile("s_waitcnt vmcnt(8)" ::: "memory");
    __builtin_amdgcn_s_barrier();

    for (int t = 0; t < nt - 3; ++t) {
        const int b = t & 3;
        phase0(b, t + 3, true);
        phase1(b, t + 3, true, 8);
    }
    phase0((nt - 3) & 3, 0, false); phase1((nt - 3) & 3, 0, false, 4);
    phase0((nt - 2) & 3, 0, false); phase1((nt - 2) & 3, 0, false, 0);
    phase0((nt - 1) & 3, 0, false); phase1((nt - 1) & 3, 0, false, -1);

    const long cBase = (long)bz * cBatch + (long)bx * BM * ldc + (long)by * BN;
    const int rg = (l >> 4) * 4;
    #pragma unroll
    for (int mi = 0; mi < MI; ++mi) {
        #pragma unroll
        for (int ni = 0; ni < NI; ++ni) {
            #pragma unroll
            for (int r = 0; r < 4; ++r) {
                int row = wrow + mi * 16 + rg + r;
                int col = wcol + ni * 16 + fr;
                float v = acc[mi][ni][r];
                if constexpr (EPI == 5) {
                    // B rows interleaved: even col = gate (wg), odd col = up (wu).
                    float pv = __shfl_xor(v, 1);   // partner lane: same row, col^1
                    if (!(fr & 1)) {
                        float gg = 0.5f * v * (1.f + tanhf(0.7978845608f * (v + 0.044715f * v * v * v)));
                        long idx5 = ((long)bx * BM + row) * (long)ldc + (long)by * (BN / 2) + (col >> 1);
                        ((__hip_bfloat16*)Cv)[idx5] = __float2bfloat16(gg * pv);
                    }
                } else {
                    long idx = cBase + (long)row * ldc + col;
                    if constexpr (EPI == 0) {
                        ((float*)Cv)[idx] = v;
                    } else if constexpr (EPI == 1) {
                        ((__hip_bfloat16*)Cv)[idx] = __float2bfloat16(v);
                    } else if constexpr (EPI == 3) {
                        ((float*)Cv)[idx] = tanhf(v * (1.f / 30.f)) * 30.f;
                    }
                }
            }
        }
    }
}

// ---------------- fallback GEMM with fp32 B staging (used only if ws too small) ----------------
template<int EPI>
__global__ __launch_bounds__(256) void gemm_f32w(
    const __hip_bfloat16* __restrict__ A, const float* __restrict__ Bv,
    void* __restrict__ Cv, int K, int lda, int ldb, int ldc) {
    __shared__ __hip_bfloat16 As[128][32];
    __shared__ __hip_bfloat16 Bs[128][32];
    const int tid = threadIdx.x;
    const __hip_bfloat16* Ab = A + (long)blockIdx.x * 128 * lda;
    const float* Bb = Bv + (long)blockIdx.y * 128 * ldb;
    const int wid = tid >> 6, lane = tid & 63;
    const int wr = (wid >> 1) * 64, wc = (wid & 1) * 64;
    const int fr = lane & 15;
    const int kb = (lane >> 4) * 8;
    floatx4 acc[4][4] = {};
    for (int k0 = 0; k0 < K; k0 += 32) {
        __syncthreads();
        #pragma unroll
        for (int it = 0; it < 2; ++it) {
            int slot = tid + it * 256;
            int r = slot >> 2, c8 = (slot & 3) * 8;
            *reinterpret_cast<uint4*>(&As[r][c8]) =
                *reinterpret_cast<const uint4*>(Ab + (long)r * lda + k0 + c8);
        }
        #pragma unroll
        for (int it = 0; it < 4; ++it) {
            int slot = tid + it * 256;
            int r = slot >> 3, c4 = (slot & 7) * 4;
            float4 f = *reinterpret_cast<const float4*>(Bb + (long)r * ldb + k0 + c4);
            __hip_bfloat16 t4[4] = {__float2bfloat16(f.x), __float2bfloat16(f.y),
                                    __float2bfloat16(f.z), __float2bfloat16(f.w)};
            *reinterpret_cast<ushort4*>(&Bs[r][c4]) = *reinterpret_cast<const ushort4*>(t4);
        }
        __syncthreads();
        bf16x8 af[4], bfr[4];
        #pragma unroll
        for (int i = 0; i < 4; ++i)
            af[i] = *reinterpret_cast<const bf16x8*>(&As[wr + i * 16 + fr][kb]);
        #pragma unroll
        for (int j = 0; j < 4; ++j)
            bfr[j] = *reinterpret_cast<const bf16x8*>(&Bs[wc + j * 16 + fr][kb]);
        #pragma unroll
        for (int i = 0; i < 4; ++i)
            #pragma unroll
            for (int j = 0; j < 4; ++j)
                acc[i][j] = __builtin_amdgcn_mfma_f32_16x16x32_bf16(af[i], bfr[j], acc[i][j], 0, 0, 0);
    }
    const long cTile = (long)blockIdx.x * 128 * ldc + (long)blockIdx.y * 128;
    const int rg = (lane >> 4) * 4;
    #pragma unroll
    for (int i = 0; i < 4; ++i)
        #pragma unroll
        for (int j = 0; j < 4; ++j)
            #pragma unroll
            for (int r = 0; r < 4; ++r) {
                int row = wr + i * 16 + rg + r;
                int col = wc + j * 16 + fr;
                long idx = cTile + (long)row * ldc + col;
                float v = acc[i][j][r];
                if constexpr (EPI == 0) ((float*)Cv)[idx] = v;
                else if constexpr (EPI == 1) ((__hip_bfloat16*)Cv)[idx] = __float2bfloat16(v);
                else if constexpr (EPI == 2) {
                    float gg = 0.5f * v * (1.f + tanhf(0.7978845608f * (v + 0.044715f * v * v * v)));
                    ((__hip_bfloat16*)Cv)[idx] = __float2bfloat16(gg);
                } else ((float*)Cv)[idx] = tanhf(v * (1.f / 30.f)) * 30.f;
            }
}

// ---------------- host ----------------
extern "C" void kernel_launch(void* const* d_in, const int* in_sizes, int n_in,
                              void* d_out, int out_size, void* d_ws, size_t ws_size,
                              hipStream_t stream) {
    const int*   ids    = (const int*)d_in[0];
    const float* embedW = (const float*)d_in[1];
    const float* wq     = (const float*)d_in[2];
    const float* wk     = (const float*)d_in[3];
    const float* wv     = (const float*)d_in[4];
    const float* wo     = (const float*)d_in[5];
    const float* wg     = (const float*)d_in[6];
    const float* wu     = (const float*)d_in[7];
    const float* wd     = (const float*)d_in[8];
    const float* ln_in  = (const float*)d_in[9];
    const float* ln_pa  = (const float*)d_in[10];
    const float* ln_pf  = (const float*)d_in[11];
    const float* ln_pff = (const float*)d_in[12];
    const float* ln_f   = (const float*)d_in[13];
    const float* w_lm   = (const float*)d_in[14];
    float* out = (float*)d_out;

    char* ws = (char*)d_ws;
    size_t off = 0;
    auto alloc = [&](size_t bytes) -> void* {
        size_t o = (off + 255) & ~(size_t)255;
        off = o + bytes;
        return (void*)(ws + o);
    };

    float* h            = (float*)alloc((size_t)S * D * 4);
    __hip_bfloat16* xb  = (__hip_bfloat16*)alloc((size_t)S * D * 2);
    __hip_bfloat16* qkvb = (__hip_bfloat16*)alloc((size_t)S * 4096 * 2); // q|k|v packed
    __hip_bfloat16* vT  = (__hip_bfloat16*)alloc((size_t)NKV * HD * S * 2);
    __hip_bfloat16* ab  = (__hip_bfloat16*)alloc((size_t)S * NH * HD * 2);
    float* tmpf         = (float*)alloc((size_t)S * D * 4);
    __hip_bfloat16* guP = (__hip_bfloat16*)alloc((size_t)S * FF * 2);    // gelu(gate)*up
    __hip_bfloat16* gu  = (__hip_bfloat16*)alloc((size_t)S * 16384 * 2); // fallback only
    float* cosb         = (float*)alloc((size_t)S * 128 * 4);
    float* sinb         = (float*)alloc((size_t)S * 128 * 4);
    __hip_bfloat16* scores = (__hip_bfloat16*)alloc((size_t)NH * S * S * 2);
    __hip_bfloat16* probs  = (__hip_bfloat16*)alloc((size_t)NH * S * S * 2);

    const long SLq = 2048L * 2048, SLkv = 1024L * 2048, SLff = 8192L * 2048;
    const long nWlm = (long)VOCAB * D;
    __hip_bfloat16* wqkvb = (__hip_bfloat16*)alloc(4L * 4096 * 2048 * 2);
    __hip_bfloat16* wgub  = (__hip_bfloat16*)alloc(4L * 16384 * 2048 * 2); // interleaved wg/wu
    __hip_bfloat16* wob   = (__hip_bfloat16*)alloc(4L * SLq * 2);
    __hip_bfloat16* wdb   = (__hip_bfloat16*)alloc(4L * SLff * 2);
    __hip_bfloat16* wlmb  = (__hip_bfloat16*)alloc(nWlm * 2);
    const bool big = (off <= ws_size);
    (void)in_sizes; (void)n_in; (void)out_size;

    rope_table_kernel<<<dim3(S), dim3(128), 0, stream>>>(cosb, sinb);
    embed_kernel<<<dim3(D / 256, S), dim3(256), 0, stream>>>(ids, embedW, h);

    auto cvt = [&](const float* s, __hip_bfloat16* dp, long n) {
        long n8 = n / 8;
        long want = (n8 + 255) / 256;
        int blocks = (int)(want < 2048 ? want : 2048);
        cvt_bf16_kernel<<<dim3(blocks), dim3(256), 0, stream>>>(s, dp, n8);
    };
    auto cvtI = [&](const float* s, __hip_bfloat16* dp, int half, long n) {
        long n8 = n / 8;
        long want = (n8 + 255) / 256;
        int blocks = (int)(want < 2048 ? want : 2048);
        cvt_inter_kernel<<<dim3(blocks), dim3(256), 0, stream>>>(s, dp, half, n8);
    };
    if (big) {
        // LM-head weights converted up-front (JIT conversion right before the LM GEMM raised
        // its HBM fetch by ~70 MB in round 9 — dirty L2/L3 collided with the GEMM's reads).
        cvt(w_lm, wlmb, nWlm);
    }

    // launchers: p256 = 256x256 2-phase (512 thr, 128 KiB LDS), p128 = 128x128 2-phase (256 thr)
    auto p256 = [&](int epi, const __hip_bfloat16* A, const __hip_bfloat16* B, void* C,
                    int K, int lda, int ldb, int ldc, int gx, int gy) {
        dim3 grid(gx * gy, 1, 1);
        if (epi == 3)
            gemm_pipe<3, 2, 4, 8, 4><<<grid, 512, 0, stream>>>(A, B, C, K, lda, ldb, ldc, 0, 0, 0, 1, gx, 0);
        else
            gemm_pipe<5, 2, 4, 8, 4><<<grid, 512, 0, stream>>>(A, B, C, K, lda, ldb, ldc, 0, 0, 0, 1, gx, 0);
    };
    auto p128 = [&](int epi, const __hip_bfloat16* A, const __hip_bfloat16* B, void* C,
                    int K, int lda, int ldb, int ldc, int gx, int gy, int gz,
                    long aB, long bB, long cB, int bzDiv, int kMode) {
        dim3 grid(gx * gy, 1, gz);
        switch (epi) {
        case 0: gemm_pipe<0, 2, 2, 4, 4><<<grid, 256, 0, stream>>>(A, B, C, K, lda, ldb, ldc, aB, bB, cB, bzDiv, gx, kMode); break;
        default: gemm_pipe<1, 2, 2, 4, 4><<<grid, 256, 0, stream>>>(A, B, C, K, lda, ldb, ldc, aB, bB, cB, bzDiv, gx, kMode); break;
        }
    };

    for (int l = 0; l < NLAYER; ++l) {
        int isLocal = (l % 2 == 0) ? 1 : 0;
        rms_bf16_kernel<<<dim3(S), dim3(256), 0, stream>>>(h, ln_in + l * D, xb);
        if (big) {
            // convert this layer's qkv weights just-in-time (L3-hot for the GEMM read)
            cvt(wq + l * SLq,  wqkvb + (size_t)l * 4096 * 2048,                SLq);
            cvt(wk + l * SLkv, wqkvb + (size_t)l * 4096 * 2048 + 2048L * 2048, SLkv);
            cvt(wv + l * SLkv, wqkvb + (size_t)l * 4096 * 2048 + 3072L * 2048, SLkv);
            p128(1, xb, wqkvb + (size_t)l * 4096 * 2048, qkvb, D, D, D, 4096, 16, 32, 1, 0, 0, 0, 1, 0);
        } else {
            gemm_f32w<1><<<dim3(16, 16), 256, 0, stream>>>(xb, wq + l * SLq, qkvb, D, D, D, 4096);
            gemm_f32w<1><<<dim3(16, 8), 256, 0, stream>>>(xb, wk + l * SLkv, qkvb + 2048, D, D, D, 4096);
            gemm_f32w<1><<<dim3(16, 8), 256, 0, stream>>>(xb, wv + l * SLkv, qkvb + 3072, D, D, D, 4096);
        }
        rope_kernel<<<dim3(S, NH), dim3(128), 0, stream>>>(qkvb, cosb, sinb, 4096);
        rope_kernel<<<dim3(S, NKV), dim3(128), 0, stream>>>(qkvb + 2048, cosb, sinb, 4096);
        transpose_v_kernel<<<dim3(S / 64, HD / 64, NKV), 256, 0, stream>>>(qkvb + 3072, vT, 4096);
        // scores = q @ k^T per head (bf16 out), masked-tile skip
        p128(1, qkvb, qkvb + 2048, scores, HD, 4096, 4096, S, 16, 16, NH,
             (long)HD, (long)HD, (long)S * S, 2, isLocal ? 2 : 1);
        softmax_kernel<<<dim3(S, NH), dim3(256), 0, stream>>>(scores, probs, isLocal);
        // a = probs @ vT, K-range restricted to valid band
        p128(1, probs, vT, ab, S, S, S, NH * HD, 16, 2, NH,
             (long)S * S, (long)HD * S, (long)HD, 2, isLocal ? 4 : 3);
        if (big) {
            cvt(wo + l * SLq, wob + (size_t)l * SLq, SLq);
            p128(0, ab, wob + (size_t)l * SLq, tmpf, NH * HD, NH * HD, NH * HD, D, 16, 16, 1, 0, 0, 0, 1, 0);
        } else {
            gemm_f32w<0><<<dim3(16, 16), 256, 0, stream>>>(ab, wo + l * SLq, tmpf, NH * HD, NH * HD, NH * HD, D);
        }
        resid_rms_kernel<<<dim3(S), dim3(256), 0, stream>>>(h, tmpf, ln_pa + l * D);
        rms_bf16_kernel<<<dim3(S), dim3(256), 0, stream>>>(h, ln_pf + l * D, xb);
        if (big) {
            cvtI(wg + l * SLff, wgub + (size_t)l * 16384 * 2048, 0, SLff);
            cvtI(wu + l * SLff, wgub + (size_t)l * 16384 * 2048, 1, SLff);
            // fused gate|up (interleaved rows), 256^2 tile; writes gelu(gate)*up -> guP [S][8192]
            p256(5, xb, wgub + (size_t)l * 16384 * 2048, guP, D, D, D, FF, 8, 64);
        } else {
            gemm_f32w<2><<<dim3(16, 64), 256, 0, stream>>>(xb, wg + l * SLff, gu, D, D, D, 16384);
            gemm_f32w<1><<<dim3(16, 64), 256, 0, stream>>>(xb, wu + l * SLff, gu + 8192, D, D, D, 16384);
            mul_gu_kernel<<<dim3((S * FF) / (256 * 8)), 256, 0, stream>>>(gu);
        }
        if (big) {
            cvt(wd + l * SLff, wdb + (size_t)l * SLff, SLff);
            p128(0, guP, wdb + (size_t)l * SLff, tmpf, FF, FF, FF, D, 16, 16, 1, 0, 0, 0, 1, 0);
        } else {
            gemm_f32w<0><<<dim3(16, 16), 256, 0, stream>>>(gu, wd + l * SLff, tmpf, FF, 16384, FF, D);
        }
        resid_rms_kernel<<<dim3(S), dim3(256), 0, stream>>>(h, tmpf, ln_pff + l * D);
    }

    rms_bf16_kernel<<<dim3(S), dim3(256), 0, stream>>>(h, ln_f, xb);
    if (big) {
        // LM head: 256^2 tile, 8 x 125 = 1000 blocks, tanh(x/30)*30 -> f32
        p256(3, xb, wlmb, out, D, D, D, VOCAB, 8, VOCAB / 256);
    } else {
        gemm_f32w<3><<<dim3(16, VOCAB / 128), 256, 0, stream>>>(xb, w_lm, out, D, D, D, VOCAB);
    }
}

// Round 12
// 2471.546 us; speedup vs baseline: 1.0948x; 1.0218x over previous
//
#include <hip/hip_runtime.h>
#include <hip/hip_bf16.h>

typedef __attribute__((ext_vector_type(8))) __bf16 bf16x8;
typedef __attribute__((ext_vector_type(4))) float floatx4;

typedef __attribute__((address_space(1))) const unsigned char kGlb;
typedef __attribute__((address_space(3))) unsigned char kLds;

static constexpr int S = 2048;
static constexpr int D = 2048;
static constexpr int HD = 256;
static constexpr int NH = 8;
static constexpr int NKV = 4;
static constexpr int NLAYER = 4;
static constexpr int VOCAB = 32000;
static constexpr int FF = 8192;
static constexpr int WINDOW = 1024;

// ---------------- block reduction helpers (256 threads = 4 waves) ----------------
__device__ __forceinline__ float blk_sum(float v) {
    __shared__ float sm[4];
    #pragma unroll
    for (int o = 32; o > 0; o >>= 1) v += __shfl_down(v, o, 64);
    int lane = threadIdx.x & 63, w = threadIdx.x >> 6;
    __syncthreads();
    if (lane == 0) sm[w] = v;
    __syncthreads();
    return sm[0] + sm[1] + sm[2] + sm[3];
}

__device__ __forceinline__ float blk_max(float v) {
    __shared__ float sm[4];
    #pragma unroll
    for (int o = 32; o > 0; o >>= 1) v = fmaxf(v, __shfl_down(v, o, 64));
    int lane = threadIdx.x & 63, w = threadIdx.x >> 6;
    __syncthreads();
    if (lane == 0) sm[w] = v;
    __syncthreads();
    return fmaxf(fmaxf(sm[0], sm[1]), fmaxf(sm[2], sm[3]));
}

// ---------------- elementwise kernels ----------------
__global__ void embed_kernel(const int* __restrict__ ids, const float* __restrict__ E,
                             float* __restrict__ h) {
    int d = blockIdx.x * 256 + threadIdx.x;
    int s = blockIdx.y;
    h[(long)s * D + d] = E[(long)ids[s] * D + d] * 45.25483399593904f; // sqrt(2048)
}

__global__ void rope_table_kernel(float* __restrict__ c, float* __restrict__ sn) {
    int i = threadIdx.x;   // 0..127
    int p = blockIdx.x;    // 0..S-1
    float inv = powf(10000.f, -(float)i / 128.f);
    float a = (float)p * inv;
    c[p * 128 + i] = cosf(a);
    sn[p * 128 + i] = sinf(a);
}

// fp32 -> bf16 conversion (grid-stride, 8 elems/thread/iter)
__global__ void cvt_bf16_kernel(const float* __restrict__ src, __hip_bfloat16* __restrict__ dst,
                                long n8) {
    long stride = (long)gridDim.x * 256;
    for (long i = (long)blockIdx.x * 256 + threadIdx.x; i < n8; i += stride) {
        long o = i * 8;
        float4 a = *(const float4*)(src + o);
        float4 b = *(const float4*)(src + o + 4);
        __hip_bfloat16 h8[8] = {
            __float2bfloat16(a.x), __float2bfloat16(a.y),
            __float2bfloat16(a.z), __float2bfloat16(a.w),
            __float2bfloat16(b.x), __float2bfloat16(b.y),
            __float2bfloat16(b.z), __float2bfloat16(b.w)};
        *(uint4*)(dst + o) = *(const uint4*)h8;
    }
}

// fp32 (rows x 2048) -> bf16 at interleaved rows: dst row = 2*row + half
__global__ void cvt_inter_kernel(const float* __restrict__ src, __hip_bfloat16* __restrict__ dst,
                                 int half, long n8) {
    long stride = (long)gridDim.x * 256;
    for (long i = (long)blockIdx.x * 256 + threadIdx.x; i < n8; i += stride) {
        long o = i * 8;
        long row = o >> 11, col = o & 2047;
        float4 a = *(const float4*)(src + o);
        float4 b = *(const float4*)(src + o + 4);
        __hip_bfloat16 h8[8] = {
            __float2bfloat16(a.x), __float2bfloat16(a.y),
            __float2bfloat16(a.z), __float2bfloat16(a.w),
            __float2bfloat16(b.x), __float2bfloat16(b.y),
            __float2bfloat16(b.z), __float2bfloat16(b.w)};
        *(uint4*)(dst + ((row * 2 + half) << 11) + col) = *(const uint4*)h8;
    }
}

// x = rms(h, w) -> bf16
__global__ void rms_bf16_kernel(const float* __restrict__ h, const float* __restrict__ w,
                                __hip_bfloat16* __restrict__ o) {
    int s = blockIdx.x;
    const float* row = h + (long)s * D;
    float vals[8], ss = 0.f;
    #pragma unroll
    for (int t = 0; t < 8; ++t) {
        int j = t * 256 + threadIdx.x;
        float v = row[j]; vals[t] = v; ss += v * v;
    }
    ss = blk_sum(ss);
    float r = rsqrtf(ss * (1.f / D) + 1e-6f);
    #pragma unroll
    for (int t = 0; t < 8; ++t) {
        int j = t * 256 + threadIdx.x;
        o[(long)s * D + j] = __float2bfloat16(vals[t] * r * (1.f + w[j]));
    }
}

// h += rms(t, w)   (fallback path only)
__global__ void resid_rms_kernel(float* __restrict__ h, const float* __restrict__ tt,
                                 const float* __restrict__ w) {
    int s = blockIdx.x;
    const float* row = tt + (long)s * D;
    float* hr = h + (long)s * D;
    float vals[8], ss = 0.f;
    #pragma unroll
    for (int t = 0; t < 8; ++t) {
        int j = t * 256 + threadIdx.x;
        float v = row[j]; vals[t] = v; ss += v * v;
    }
    ss = blk_sum(ss);
    float r = rsqrtf(ss * (1.f / D) + 1e-6f);
    #pragma unroll
    for (int t = 0; t < 8; ++t) {
        int j = t * 256 + threadIdx.x;
        hr[j] += vals[t] * r * (1.f + w[j]);
    }
}

// Fused: tv = t0+t1 (split-K partials); h += rms(tv, w1); xb = rms(h, w2)
__global__ void resid2_rms_kernel(float* __restrict__ h, const float* __restrict__ t0,
                                  const float* __restrict__ t1, const float* __restrict__ w1,
                                  const float* __restrict__ w2, __hip_bfloat16* __restrict__ xb) {
    int s = blockIdx.x;
    const float* r0 = t0 + (long)s * D;
    const float* r1 = t1 + (long)s * D;
    float* hr = h + (long)s * D;
    float vals[8], ss = 0.f;
    #pragma unroll
    for (int t = 0; t < 8; ++t) {
        int j = t * 256 + threadIdx.x;
        float v = r0[j] + r1[j]; vals[t] = v; ss += v * v;
    }
    ss = blk_sum(ss);
    float r = rsqrtf(ss * (1.f / D) + 1e-6f);
    float hv[8], ss2 = 0.f;
    #pragma unroll
    for (int t = 0; t < 8; ++t) {
        int j = t * 256 + threadIdx.x;
        float nh = hr[j] + vals[t] * r * (1.f + w1[j]);
        hv[t] = nh; hr[j] = nh; ss2 += nh * nh;
    }
    ss2 = blk_sum(ss2);
    float r2 = rsqrtf(ss2 * (1.f / D) + 1e-6f);
    #pragma unroll
    for (int t = 0; t < 8; ++t) {
        int j = t * 256 + threadIdx.x;
        xb[(long)s * D + j] = __float2bfloat16(hv[t] * r2 * (1.f + w2[j]));
    }
}

// in-place RoPE on rows with stride ldx; head offset hh*HD; 128 threads per (s, head)
__global__ void rope_kernel(__hip_bfloat16* __restrict__ x, const float* __restrict__ cb,
                            const float* __restrict__ sb, int ldx) {
    int s = blockIdx.x, hh = blockIdx.y, i = threadIdx.x; // i in 0..127
    __hip_bfloat16* p = x + (long)s * ldx + hh * HD;
    float x1 = __bfloat162float(p[i]);
    float x2 = __bfloat162float(p[128 + i]);
    float c = cb[s * 128 + i], sn = sb[s * 128 + i];
    p[i]       = __float2bfloat16(x1 * c - x2 * sn);
    p[128 + i] = __float2bfloat16(x1 * sn + x2 * c);
}

// v rows (stride ldv) -> vT (NKV, HD, S) bf16
__global__ void transpose_v_kernel(const __hip_bfloat16* __restrict__ v,
                                   __hip_bfloat16* __restrict__ vt, int ldv) {
    __shared__ ushort tile[64][65];
    int s0 = blockIdx.x * 64, d0 = blockIdx.y * 64, kv = blockIdx.z;
    const ushort* vin = (const ushort*)v;
    ushort* vout = (ushort*)vt;
    #pragma unroll
    for (int it = 0; it < 4; ++it) {
        int slot = it * 256 + threadIdx.x;
        int r = slot >> 4, c4 = (slot & 15) << 2;
        ushort4 x = *(const ushort4*)(vin + (long)(s0 + r) * ldv + kv * HD + d0 + c4);
        tile[r][c4] = x.x; tile[r][c4 + 1] = x.y; tile[r][c4 + 2] = x.z; tile[r][c4 + 3] = x.w;
    }
    __syncthreads();
    #pragma unroll
    for (int it = 0; it < 4; ++it) {
        int slot = it * 256 + threadIdx.x;
        int rr = slot >> 4, c4 = (slot & 15) << 2;
        ushort4 y;
        y.x = tile[c4][rr]; y.y = tile[c4 + 1][rr]; y.z = tile[c4 + 2][rr]; y.w = tile[c4 + 3][rr];
        *(ushort4*)(vout + (long)kv * HD * S + (long)(d0 + rr) * S + s0 + c4) = y;
    }
}

// scores (NH,S,S) bf16 -> probs bf16, with scale, tanh softcap, mask, softmax.
__global__ void softmax_kernel(const __hip_bfloat16* __restrict__ sc,
                               __hip_bfloat16* __restrict__ pr, int isLocal) {
    int i = blockIdx.x, hh = blockIdx.y;
    const __hip_bfloat16* row = sc + ((long)hh * S + i) * S;
    __hip_bfloat16* orow = pr + ((long)hh * S + i) * S;
    int lo = isLocal ? max(0, i - (WINDOW - 1)) : 0;
    float vals[8];
    float m = -3.0e38f;
    #pragma unroll
    for (int t = 0; t < 8; ++t) {
        int j = t * 256 + threadIdx.x;
        bool chunkAny = (t * 256 <= i) && (t * 256 + 255 >= lo);
        if (chunkAny) {
            bool valid = (j <= i) && (j >= lo);
            float v = tanhf(__bfloat162float(row[j]) * (0.0625f / 50.f)) * 50.f;
            vals[t] = valid ? v : -3.0e38f;
            m = fmaxf(m, vals[t]);
        } else {
            vals[t] = -3.0e38f;
        }
    }
    m = blk_max(m);
    float ps[8], ssum = 0.f;
    #pragma unroll
    for (int t = 0; t < 8; ++t) {
        float p = (vals[t] > -1.0e38f) ? __expf(vals[t] - m) : 0.f;
        ps[t] = p; ssum += p;
    }
    ssum = blk_sum(ssum);
    float inv = 1.f / ssum;
    #pragma unroll
    for (int t = 0; t < 8; ++t) {
        int j = t * 256 + threadIdx.x;
        orow[j] = __float2bfloat16(ps[t] * inv);
    }
}

// gate half *= up half, packed gu[S][16384] (fallback path only)
__global__ void mul_gu_kernel(__hip_bfloat16* __restrict__ gu) {
    long idx = ((long)blockIdx.x * 256 + threadIdx.x) * 8;
    long s = idx >> 13;
    long f = idx & 8191;
    __hip_bfloat16* gp = gu + s * 16384 + f;
    const __hip_bfloat16* up = gu + s * 16384 + 8192 + f;
    uint4 gv = *(const uint4*)gp;
    uint4 uv = *(const uint4*)up;
    const __hip_bfloat16* gb = (const __hip_bfloat16*)&gv;
    const __hip_bfloat16* ub = (const __hip_bfloat16*)&uv;
    __hip_bfloat16 o[8];
    #pragma unroll
    for (int j = 0; j < 8; ++j)
        o[j] = __float2bfloat16(__bfloat162float(gb[j]) * __bfloat162float(ub[j]));
    *(uint4*)gp = *(const uint4*)o;
}

// ---------------- generic pipelined GEMM: C[M,N] = A[M,K] * B[N,K]^T, bf16 ----------------
// Tile BM=WM*MI*16 x BN=WN*NI*16, BK=32, threads T=WM*WN*64 (BM==BN==T/2 required by staging).
// 4 LDS buffers, depth-3 prefetch, 2 sub-phases/K-tile, counted vmcnt(8), setprio around MFMA,
// both-sides XOR swizzle, XCD-chunked 1-D grid remap (nwg % 8 == 0).
// 128^2 (256 thr, 64 KiB LDS -> 2 blocks/CU): activations/attention GEMMs.
// 256^2 (512 thr, 128 KiB): gate|up + LM head (panel reuse fits L3; at 128^2 the LM head
//   fetched 595 MB vs 214 MB in round 10).
// EPI: 0=f32, 1=bf16, 3=tanh(x/30)*30->f32 (LM head),
//      5=interleaved gelu(gate)*up -> bf16 (B rows interleaved wg/wu)
// kMode: 0 none; 1 causal score-tile skip; 2 local score-tile skip; 3 causal PV K-range;
//        4 local PV K-range; 5 split-K over z (bz picks K-half; C offset bz*cBatch)
template<int EPI, int WM, int WN, int MI, int NI>
__global__ __launch_bounds__(WM*WN*64, 2) void gemm_pipe(
    const __hip_bfloat16* __restrict__ A, const __hip_bfloat16* __restrict__ B,
    void* __restrict__ Cv, int K, int lda, int ldb, int ldc,
    long aBatch, long bBatch, long cBatch, int bzDiv, int gx, int kMode) {
    constexpr int T  = WM * WN * 64;
    constexpr int BM = WM * MI * 16;
    constexpr int BN = WN * NI * 16;
    constexpr int AE = BM * 32;
    constexpr int BE = BN * 32;
    __shared__ __hip_bfloat16 lds[4][AE + BE];

    const int tid = threadIdx.x;
    const int nwg = gridDim.x;
    const int orig = blockIdx.x;
    const int wgid = (orig & 7) * (nwg >> 3) + (orig >> 3);
    const int bx = wgid % gx, by = wgid / gx;
    const int bz = blockIdx.z;

    int kstart = 0, kend = K;
    if (kMode == 1) { if (by > bx) return; }
    else if (kMode == 2) { if (by > bx || bx - by >= 9) return; }
    else if (kMode == 3) { kend = min(K, (bx + 1) * BM); }
    else if (kMode == 4) { kend = min(K, (bx + 1) * BM); kstart = max(0, (bx - 1024 / BM) * BM); }
    else if (kMode == 5) { int hk = K >> 1; kstart = bz * hk; kend = kstart + hk; }

    const __hip_bfloat16* Ab = A + (long)bz * aBatch + (long)bx * BM * lda;
    const __hip_bfloat16* Bb = B + (long)(bz / bzDiv) * bBatch + (long)by * BN * ldb;

    const int w = tid >> 6, l = tid & 63;
    const int wm = w / WN, wn = w % WN;
    const int wrow = wm * MI * 16, wcol = wn * NI * 16;
    const int fr = l & 15, g = l >> 4;
    const int sR = tid >> 2;
    const int sc = tid & 3;

    floatx4 acc[MI][NI] = {};
    bf16x8 bfv[NI];
    bf16x8 af[MI / 2];

    auto stageA = [&](int t, int buf) {
        const int k0 = kstart + t * 32;
        #pragma unroll
        for (int i = 0; i < 2; ++i) {
            int row = sR + i * (T / 4);
            int scol = ((sc ^ ((row >> 1) & 3)) << 3);
            __builtin_amdgcn_global_load_lds(
                (kGlb*)(Ab + (long)row * lda + k0 + scol),
                (kLds*)(&lds[buf][0] + tid * 8 + i * (T * 8)), 16, 0, 0);
        }
    };
    auto stageB = [&](int t, int buf) {
        const int k0 = kstart + t * 32;
        #pragma unroll
        for (int i = 0; i < 2; ++i) {
            int row = sR + i * (T / 4);
            int scol = ((sc ^ ((row >> 1) & 3)) << 3);
            __builtin_amdgcn_global_load_lds(
                (kGlb*)(Bb + (long)row * ldb + k0 + scol),
                (kLds*)(&lds[buf][AE] + tid * 8 + i * (T * 8)), 16, 0, 0);
        }
    };

    auto phase0 = [&](int buf, int t3, bool doStage) {
        const char* AsB = (const char*)&lds[buf][0];
        const char* BsB = (const char*)&lds[buf][AE];
        #pragma unroll
        for (int mi = 0; mi < MI / 2; ++mi) {
            int ra = wrow + mi * 16 + fr;
            af[mi] = *(const bf16x8*)(AsB + ra * 64 + ((g ^ ((ra >> 1) & 3)) << 4));
        }
        #pragma unroll
        for (int ni = 0; ni < NI; ++ni) {
            int rb = wcol + ni * 16 + fr;
            bfv[ni] = *(const bf16x8*)(BsB + rb * 64 + ((g ^ ((rb >> 1) & 3)) << 4));
        }
        if (doStage) stageA(t3, t3 & 3);
        __builtin_amdgcn_s_barrier();
        asm volatile("s_waitcnt lgkmcnt(0)" ::: "memory");
        __builtin_amdgcn_sched_barrier(0);
        __builtin_amdgcn_s_setprio(1);
        #pragma unroll
        for (int mi = 0; mi < MI / 2; ++mi)
            #pragma unroll
            for (int ni = 0; ni < NI; ++ni)
                acc[mi][ni] = __builtin_amdgcn_mfma_f32_16x16x32_bf16(af[mi], bfv[ni], acc[mi][ni], 0, 0, 0);
        __builtin_amdgcn_s_setprio(0);
        __builtin_amdgcn_sched_barrier(0);
        __builtin_amdgcn_s_barrier();
    };

    auto phase1 = [&](int buf, int t3, bool doStage, int vm) {
        const char* AsB = (const char*)&lds[buf][0];
        #pragma unroll
        for (int mi = 0; mi < MI / 2; ++mi) {
            int ra = wrow + (MI / 2 + mi) * 16 + fr;
            af[mi] = *(const bf16x8*)(AsB + ra * 64 + ((g ^ ((ra >> 1) & 3)) << 4));
        }
        if (doStage) stageB(t3, t3 & 3);
        if (vm == 8)      asm volatile("s_waitcnt vmcnt(8)" ::: "memory");
        else if (vm == 4) asm volatile("s_waitcnt vmcnt(4)" ::: "memory");
        else if (vm == 0) asm volatile("s_waitcnt vmcnt(0)" ::: "memory");
        __builtin_amdgcn_s_barrier();
        asm volatile("s_waitcnt lgkmcnt(0)" ::: "memory");
        __builtin_amdgcn_sched_barrier(0);
        __builtin_amdgcn_s_setprio(1);
        #pragma unroll
        for (int mi = 0; mi < MI / 2; ++mi)
            #pragma unroll
            for (int ni = 0; ni < NI; ++ni)
                acc[MI / 2 + mi][ni] = __builtin_amdgcn_mfma_f32_16x16x32_bf16(af[mi], bfv[ni], acc[MI / 2 + mi][ni], 0, 0, 0);
        __builtin_amdgcn_s_setprio(0);
        __builtin_amdgcn_sched_barrier(0);
        __builtin_amdgcn_s_barrier();
    };

    const int nt = (kend - kstart) >> 5;
    stageA(0, 0); stageB(0, 0);
    stageA(1, 1); stageB(1, 1);
    stageA(2, 2); stageB(2, 2);
    asm volatile("s_waitcnt vmcnt(8)" ::: "memory");
    __builtin_amdgcn_s_barrier();

    for (int t = 0; t < nt - 3; ++t) {
        const int b = t & 3;
        phase0(b, t + 3, true);
        phase1(b, t + 3, true, 8);
    }
    phase0((nt - 3) & 3, 0, false); phase1((nt - 3) & 3, 0, false, 4);
    phase0((nt - 2) & 3, 0, false); phase1((nt - 2) & 3, 0, false, 0);
    phase0((nt - 1) & 3, 0, false); phase1((nt - 1) & 3, 0, false, -1);

    const long cBase = (long)bz * cBatch + (long)bx * BM * ldc + (long)by * BN;
    const int rg = (l >> 4) * 4;
    #pragma unroll
    for (int mi = 0; mi < MI; ++mi) {
        #pragma unroll
        for (int ni = 0; ni < NI; ++ni) {
            #pragma unroll
            for (int r = 0; r < 4; ++r) {
                int row = wrow + mi * 16 + rg + r;
                int col = wcol + ni * 16 + fr;
                float v = acc[mi][ni][r];
                if constexpr (EPI == 5) {
                    // B rows interleaved: even col = gate (wg), odd col = up (wu).
                    float pv = __shfl_xor(v, 1);   // partner lane: same row, col^1
                    if (!(fr & 1)) {
                        float gg = 0.5f * v * (1.f + tanhf(0.7978845608f * (v + 0.044715f * v * v * v)));
                        long idx5 = ((long)bx * BM + row) * (long)ldc + (long)by * (BN / 2) + (col >> 1);
                        ((__hip_bfloat16*)Cv)[idx5] = __float2bfloat16(gg * pv);
                    }
                } else {
                    long idx = cBase + (long)row * ldc + col;
                    if constexpr (EPI == 0) {
                        ((float*)Cv)[idx] = v;
                    } else if constexpr (EPI == 1) {
                        ((__hip_bfloat16*)Cv)[idx] = __float2bfloat16(v);
                    } else if constexpr (EPI == 3) {
                        ((float*)Cv)[idx] = tanhf(v * (1.f / 30.f)) * 30.f;
                    }
                }
            }
        }
    }
}

// ---------------- fallback GEMM with fp32 B staging (used only if ws too small) ----------------
template<int EPI>
__global__ __launch_bounds__(256) void gemm_f32w(
    const __hip_bfloat16* __restrict__ A, const float* __restrict__ Bv,
    void* __restrict__ Cv, int K, int lda, int ldb, int ldc) {
    __shared__ __hip_bfloat16 As[128][32];
    __shared__ __hip_bfloat16 Bs[128][32];
    const int tid = threadIdx.x;
    const __hip_bfloat16* Ab = A + (long)blockIdx.x * 128 * lda;
    const float* Bb = Bv + (long)blockIdx.y * 128 * ldb;
    const int wid = tid >> 6, lane = tid & 63;
    const int wr = (wid >> 1) * 64, wc = (wid & 1) * 64;
    const int fr = lane & 15;
    const int kb = (lane >> 4) * 8;
    floatx4 acc[4][4] = {};
    for (int k0 = 0; k0 < K; k0 += 32) {
        __syncthreads();
        #pragma unroll
        for (int it = 0; it < 2; ++it) {
            int slot = tid + it * 256;
            int r = slot >> 2, c8 = (slot & 3) * 8;
            *reinterpret_cast<uint4*>(&As[r][c8]) =
                *reinterpret_cast<const uint4*>(Ab + (long)r * lda + k0 + c8);
        }
        #pragma unroll
        for (int it = 0; it < 4; ++it) {
            int slot = tid + it * 256;
            int r = slot >> 3, c4 = (slot & 7) * 4;
            float4 f = *reinterpret_cast<const float4*>(Bb + (long)r * ldb + k0 + c4);
            __hip_bfloat16 t4[4] = {__float2bfloat16(f.x), __float2bfloat16(f.y),
                                    __float2bfloat16(f.z), __float2bfloat16(f.w)};
            *reinterpret_cast<ushort4*>(&Bs[r][c4]) = *reinterpret_cast<const ushort4*>(t4);
        }
        __syncthreads();
        bf16x8 af[4], bfr[4];
        #pragma unroll
        for (int i = 0; i < 4; ++i)
            af[i] = *reinterpret_cast<const bf16x8*>(&As[wr + i * 16 + fr][kb]);
        #pragma unroll
        for (int j = 0; j < 4; ++j)
            bfr[j] = *reinterpret_cast<const bf16x8*>(&Bs[wc + j * 16 + fr][kb]);
        #pragma unroll
        for (int i = 0; i < 4; ++i)
            #pragma unroll
            for (int j = 0; j < 4; ++j)
                acc[i][j] = __builtin_amdgcn_mfma_f32_16x16x32_bf16(af[i], bfr[j], acc[i][j], 0, 0, 0);
    }
    const long cTile = (long)blockIdx.x * 128 * ldc + (long)blockIdx.y * 128;
    const int rg = (lane >> 4) * 4;
    #pragma unroll
    for (int i = 0; i < 4; ++i)
        #pragma unroll
        for (int j = 0; j < 4; ++j)
            #pragma unroll
            for (int r = 0; r < 4; ++r) {
                int row = wr + i * 16 + rg + r;
                int col = wc + j * 16 + fr;
                long idx = cTile + (long)row * ldc + col;
                float v = acc[i][j][r];
                if constexpr (EPI == 0) ((float*)Cv)[idx] = v;
                else if constexpr (EPI == 1) ((__hip_bfloat16*)Cv)[idx] = __float2bfloat16(v);
                else if constexpr (EPI == 2) {
                    float gg = 0.5f * v * (1.f + tanhf(0.7978845608f * (v + 0.044715f * v * v * v)));
                    ((__hip_bfloat16*)Cv)[idx] = __float2bfloat16(gg);
                } else ((float*)Cv)[idx] = tanhf(v * (1.f / 30.f)) * 30.f;
            }
}

// ---------------- host ----------------
extern "C" void kernel_launch(void* const* d_in, const int* in_sizes, int n_in,
                              void* d_out, int out_size, void* d_ws, size_t ws_size,
                              hipStream_t stream) {
    const int*   ids    = (const int*)d_in[0];
    const float* embedW = (const float*)d_in[1];
    const float* wq     = (const float*)d_in[2];
    const float* wk     = (const float*)d_in[3];
    const float* wv     = (const float*)d_in[4];
    const float* wo     = (const float*)d_in[5];
    const float* wg     = (const float*)d_in[6];
    const float* wu     = (const float*)d_in[7];
    const float* wd     = (const float*)d_in[8];
    const float* ln_in  = (const float*)d_in[9];
    const float* ln_pa  = (const float*)d_in[10];
    const float* ln_pf  = (const float*)d_in[11];
    const float* ln_pff = (const float*)d_in[12];
    const float* ln_f   = (const float*)d_in[13];
    const float* w_lm   = (const float*)d_in[14];
    float* out = (float*)d_out;

    char* ws = (char*)d_ws;
    size_t off = 0;
    auto alloc = [&](size_t bytes) -> void* {
        size_t o = (off + 255) & ~(size_t)255;
        off = o + bytes;
        return (void*)(ws + o);
    };

    float* h            = (float*)alloc((size_t)S * D * 4);
    __hip_bfloat16* xb  = (__hip_bfloat16*)alloc((size_t)S * D * 2);
    __hip_bfloat16* qkvb = (__hip_bfloat16*)alloc((size_t)S * 4096 * 2); // q|k|v packed
    __hip_bfloat16* vT  = (__hip_bfloat16*)alloc((size_t)NKV * HD * S * 2);
    __hip_bfloat16* ab  = (__hip_bfloat16*)alloc((size_t)S * NH * HD * 2);
    float* tmpf         = (float*)alloc((size_t)S * D * 4 * 2);   // two split-K partials
    float* tmpf2        = tmpf + (size_t)S * D;
    __hip_bfloat16* guP = (__hip_bfloat16*)alloc((size_t)S * FF * 2);    // gelu(gate)*up
    __hip_bfloat16* gu  = (__hip_bfloat16*)alloc((size_t)S * 16384 * 2); // fallback only
    float* cosb         = (float*)alloc((size_t)S * 128 * 4);
    float* sinb         = (float*)alloc((size_t)S * 128 * 4);
    __hip_bfloat16* scores = (__hip_bfloat16*)alloc((size_t)NH * S * S * 2);
    __hip_bfloat16* probs  = (__hip_bfloat16*)alloc((size_t)NH * S * S * 2);

    const long SLq = 2048L * 2048, SLkv = 1024L * 2048, SLff = 8192L * 2048;
    const long nWlm = (long)VOCAB * D;
    __hip_bfloat16* wqkvb = (__hip_bfloat16*)alloc(4L * 4096 * 2048 * 2);
    __hip_bfloat16* wgub  = (__hip_bfloat16*)alloc(4L * 16384 * 2048 * 2); // interleaved wg/wu
    __hip_bfloat16* wob   = (__hip_bfloat16*)alloc(4L * SLq * 2);
    __hip_bfloat16* wdb   = (__hip_bfloat16*)alloc(4L * SLff * 2);
    __hip_bfloat16* wlmb  = (__hip_bfloat16*)alloc(nWlm * 2);
    const bool big = (off <= ws_size);
    (void)in_sizes; (void)n_in; (void)out_size;

    rope_table_kernel<<<dim3(S), dim3(128), 0, stream>>>(cosb, sinb);
    embed_kernel<<<dim3(D / 256, S), dim3(256), 0, stream>>>(ids, embedW, h);

    auto cvt = [&](const float* s, __hip_bfloat16* dp, long n) {
        long n8 = n / 8;
        long want = (n8 + 255) / 256;
        int blocks = (int)(want < 2048 ? want : 2048);
        cvt_bf16_kernel<<<dim3(blocks), dim3(256), 0, stream>>>(s, dp, n8);
    };
    auto cvtI = [&](const float* s, __hip_bfloat16* dp, int half, long n) {
        long n8 = n / 8;
        long want = (n8 + 255) / 256;
        int blocks = (int)(want < 2048 ? want : 2048);
        cvt_inter_kernel<<<dim3(blocks), dim3(256), 0, stream>>>(s, dp, half, n8);
    };
    if (big) {
        // LM-head weights converted up-front (JIT conversion right before the LM GEMM raised
        // its HBM fetch by ~70 MB in round 9 — dirty L2/L3 collided with the GEMM's reads).
        cvt(w_lm, wlmb, nWlm);
    }

    // launchers: p256 = 256x256 2-phase (512 thr, 128 KiB LDS), p128 = 128x128 2-phase (256 thr)
    auto p256 = [&](int epi, const __hip_bfloat16* A, const __hip_bfloat16* B, void* C,
                    int K, int lda, int ldb, int ldc, int gx, int gy) {
        dim3 grid(gx * gy, 1, 1);
        if (epi == 3)
            gemm_pipe<3, 2, 4, 8, 4><<<grid, 512, 0, stream>>>(A, B, C, K, lda, ldb, ldc, 0, 0, 0, 1, gx, 0);
        else
            gemm_pipe<5, 2, 4, 8, 4><<<grid, 512, 0, stream>>>(A, B, C, K, lda, ldb, ldc, 0, 0, 0, 1, gx, 0);
    };
    auto p128 = [&](int epi, const __hip_bfloat16* A, const __hip_bfloat16* B, void* C,
                    int K, int lda, int ldb, int ldc, int gx, int gy, int gz,
                    long aB, long bB, long cB, int bzDiv, int kMode) {
        dim3 grid(gx * gy, 1, gz);
        switch (epi) {
        case 0: gemm_pipe<0, 2, 2, 4, 4><<<grid, 256, 0, stream>>>(A, B, C, K, lda, ldb, ldc, aB, bB, cB, bzDiv, gx, kMode); break;
        default: gemm_pipe<1, 2, 2, 4, 4><<<grid, 256, 0, stream>>>(A, B, C, K, lda, ldb, ldc, aB, bB, cB, bzDiv, gx, kMode); break;
        }
    };

    if (big) {
        // x = rms(h, ln_in[0]) for layer 0 (subsequent layers get xb from the fused kernel)
        rms_bf16_kernel<<<dim3(S), dim3(256), 0, stream>>>(h, ln_in, xb);
        for (int l = 0; l < NLAYER; ++l) {
            int isLocal = (l % 2 == 0) ? 1 : 0;
            // convert this layer's qkv weights just-in-time (L3-hot for the GEMM read)
            cvt(wq + l * SLq,  wqkvb + (size_t)l * 4096 * 2048,                SLq);
            cvt(wk + l * SLkv, wqkvb + (size_t)l * 4096 * 2048 + 2048L * 2048, SLkv);
            cvt(wv + l * SLkv, wqkvb + (size_t)l * 4096 * 2048 + 3072L * 2048, SLkv);
            p128(1, xb, wqkvb + (size_t)l * 4096 * 2048, qkvb, D, D, D, 4096, 16, 32, 1, 0, 0, 0, 1, 0);
            rope_kernel<<<dim3(S, NH), dim3(128), 0, stream>>>(qkvb, cosb, sinb, 4096);
            rope_kernel<<<dim3(S, NKV), dim3(128), 0, stream>>>(qkvb + 2048, cosb, sinb, 4096);
            transpose_v_kernel<<<dim3(S / 64, HD / 64, NKV), 256, 0, stream>>>(qkvb + 3072, vT, 4096);
            // scores = q @ k^T per head (bf16 out), masked-tile skip
            p128(1, qkvb, qkvb + 2048, scores, HD, 4096, 4096, S, 16, 16, NH,
                 (long)HD, (long)HD, (long)S * S, 2, isLocal ? 2 : 1);
            softmax_kernel<<<dim3(S, NH), dim3(256), 0, stream>>>(scores, probs, isLocal);
            // a = probs @ vT, K-range restricted to valid band
            p128(1, probs, vT, ab, S, S, S, NH * HD, 16, 2, NH,
                 (long)S * S, (long)HD * S, (long)HD, 2, isLocal ? 4 : 3);
            // attn out projection, split-K=2 (512 blocks -> 2 blocks/CU)
            cvt(wo + l * SLq, wob + (size_t)l * SLq, SLq);
            p128(0, ab, wob + (size_t)l * SLq, tmpf, NH * HD, NH * HD, NH * HD, D,
                 16, 16, 2, 0, 0, (long)S * D, 1, 5);
            // h += rms(tmpf+tmpf2, ln_pa); xb = rms(h, ln_pf)
            resid2_rms_kernel<<<dim3(S), dim3(256), 0, stream>>>(
                h, tmpf, tmpf2, ln_pa + l * D, ln_pf + l * D, xb);
            // fused gate|up (interleaved rows), 256^2 tile; writes gelu(gate)*up -> guP [S][8192]
            cvtI(wg + l * SLff, wgub + (size_t)l * 16384 * 2048, 0, SLff);
            cvtI(wu + l * SLff, wgub + (size_t)l * 16384 * 2048, 1, SLff);
            p256(5, xb, wgub + (size_t)l * 16384 * 2048, guP, D, D, D, FF, 8, 64);
            // down projection, split-K=2
            cvt(wd + l * SLff, wdb + (size_t)l * SLff, SLff);
            p128(0, guP, wdb + (size_t)l * SLff, tmpf, FF, FF, FF, D,
                 16, 16, 2, 0, 0, (long)S * D, 1, 5);
            // h += rms(tmpf+tmpf2, ln_pff); xb = rms(h, next-op weight)
            const float* wNext = (l < NLAYER - 1) ? (ln_in + (l + 1) * D) : ln_f;
            resid2_rms_kernel<<<dim3(S), dim3(256), 0, stream>>>(
                h, tmpf, tmpf2, ln_pff + l * D, wNext, xb);
        }
        // LM head: 256^2 tile, 8 x 125 = 1000 blocks, tanh(x/30)*30 -> f32
        p256(3, xb, wlmb, out, D, D, D, VOCAB, 8, VOCAB / 256);
    } else {
        for (int l = 0; l < NLAYER; ++l) {
            int isLocal = (l % 2 == 0) ? 1 : 0;
            rms_bf16_kernel<<<dim3(S), dim3(256), 0, stream>>>(h, ln_in + l * D, xb);
            gemm_f32w<1><<<dim3(16, 16), 256, 0, stream>>>(xb, wq + l * SLq, qkvb, D, D, D, 4096);
            gemm_f32w<1><<<dim3(16, 8), 256, 0, stream>>>(xb, wk + l * SLkv, qkvb + 2048, D, D, D, 4096);
            gemm_f32w<1><<<dim3(16, 8), 256, 0, stream>>>(xb, wv + l * SLkv, qkvb + 3072, D, D, D, 4096);
            rope_kernel<<<dim3(S, NH), dim3(128), 0, stream>>>(qkvb, cosb, sinb, 4096);
            rope_kernel<<<dim3(S, NKV), dim3(128), 0, stream>>>(qkvb + 2048, cosb, sinb, 4096);
            transpose_v_kernel<<<dim3(S / 64, HD / 64, NKV), 256, 0, stream>>>(qkvb + 3072, vT, 4096);
            p128(1, qkvb, qkvb + 2048, scores, HD, 4096, 4096, S, 16, 16, NH,
                 (long)HD, (long)HD, (long)S * S, 2, isLocal ? 2 : 1);
            softmax_kernel<<<dim3(S, NH), dim3(256), 0, stream>>>(scores, probs, isLocal);
            p128(1, probs, vT, ab, S, S, S, NH * HD, 16, 2, NH,
                 (long)S * S, (long)HD * S, (long)HD, 2, isLocal ? 4 : 3);
            gemm_f32w<0><<<dim3(16, 16), 256, 0, stream>>>(ab, wo + l * SLq, tmpf, NH * HD, NH * HD, NH * HD, D);
            resid_rms_kernel<<<dim3(S), dim3(256), 0, stream>>>(h, tmpf, ln_pa + l * D);
            rms_bf16_kernel<<<dim3(S), dim3(256), 0, stream>>>(h, ln_pf + l * D, xb);
            gemm_f32w<2><<<dim3(16, 64), 256, 0, stream>>>(xb, wg + l * SLff, gu, D, D, D, 16384);
            gemm_f32w<1><<<dim3(16, 64), 256, 0, stream>>>(xb, wu + l * SLff, gu + 8192, D, D, D, 16384);
            mul_gu_kernel<<<dim3((S * FF) / (256 * 8)), 256, 0, stream>>>(gu);
            gemm_f32w<0><<<dim3(16, 16), 256, 0, stream>>>(gu, wd + l * SLff, tmpf, FF, 16384, FF, D);
            resid_rms_kernel<<<dim3(S), dim3(256), 0, stream>>>(h, tmpf, ln_pff + l * D);
        }
        rms_bf16_kernel<<<dim3(S), dim3(256), 0, stream>>>(h, ln_f, xb);
        gemm_f32w<3><<<dim3(16, VOCAB / 128), 256, 0, stream>>>(xb, w_lm, out, D, D, D, VOCAB);
    }
}

// Round 13
// 2427.086 us; speedup vs baseline: 1.1148x; 1.0183x over previous
//
#include <hip/hip_runtime.h>
#include <hip/hip_bf16.h>

typedef __attribute__((ext_vector_type(8))) __bf16 bf16x8;
typedef __attribute__((ext_vector_type(4))) float floatx4;

typedef __attribute__((address_space(1))) const unsigned char kGlb;
typedef __attribute__((address_space(3))) unsigned char kLds;

static constexpr int S = 2048;
static constexpr int D = 2048;
static constexpr int HD = 256;
static constexpr int NH = 8;
static constexpr int NKV = 4;
static constexpr int NLAYER = 4;
static constexpr int VOCAB = 32000;
static constexpr int FF = 8192;
static constexpr int WINDOW = 1024;

// ---------------- block reduction helpers (256 threads = 4 waves) ----------------
__device__ __forceinline__ float blk_sum(float v) {
    __shared__ float sm[4];
    #pragma unroll
    for (int o = 32; o > 0; o >>= 1) v += __shfl_down(v, o, 64);
    int lane = threadIdx.x & 63, w = threadIdx.x >> 6;
    __syncthreads();
    if (lane == 0) sm[w] = v;
    __syncthreads();
    return sm[0] + sm[1] + sm[2] + sm[3];
}

__device__ __forceinline__ float blk_max(float v) {
    __shared__ float sm[4];
    #pragma unroll
    for (int o = 32; o > 0; o >>= 1) v = fmaxf(v, __shfl_down(v, o, 64));
    int lane = threadIdx.x & 63, w = threadIdx.x >> 6;
    __syncthreads();
    if (lane == 0) sm[w] = v;
    __syncthreads();
    return fmaxf(fmaxf(sm[0], sm[1]), fmaxf(sm[2], sm[3]));
}

// ---------------- elementwise kernels ----------------
__global__ void embed_kernel(const int* __restrict__ ids, const float* __restrict__ E,
                             float* __restrict__ h) {
    int d = blockIdx.x * 256 + threadIdx.x;
    int s = blockIdx.y;
    h[(long)s * D + d] = E[(long)ids[s] * D + d] * 45.25483399593904f; // sqrt(2048)
}

__global__ void rope_table_kernel(float* __restrict__ c, float* __restrict__ sn) {
    int i = threadIdx.x;   // 0..127
    int p = blockIdx.x;    // 0..S-1
    float inv = powf(10000.f, -(float)i / 128.f);
    float a = (float)p * inv;
    c[p * 128 + i] = cosf(a);
    sn[p * 128 + i] = sinf(a);
}

// fp32 -> bf16 conversion (grid-stride, 8 elems/thread/iter)
__global__ void cvt_bf16_kernel(const float* __restrict__ src, __hip_bfloat16* __restrict__ dst,
                                long n8) {
    long stride = (long)gridDim.x * 256;
    for (long i = (long)blockIdx.x * 256 + threadIdx.x; i < n8; i += stride) {
        long o = i * 8;
        float4 a = *(const float4*)(src + o);
        float4 b = *(const float4*)(src + o + 4);
        __hip_bfloat16 h8[8] = {
            __float2bfloat16(a.x), __float2bfloat16(a.y),
            __float2bfloat16(a.z), __float2bfloat16(a.w),
            __float2bfloat16(b.x), __float2bfloat16(b.y),
            __float2bfloat16(b.z), __float2bfloat16(b.w)};
        *(uint4*)(dst + o) = *(const uint4*)h8;
    }
}

// fp32 (rows x 2048) -> bf16 at interleaved rows: dst row = 2*row + half
__global__ void cvt_inter_kernel(const float* __restrict__ src, __hip_bfloat16* __restrict__ dst,
                                 int half, long n8) {
    long stride = (long)gridDim.x * 256;
    for (long i = (long)blockIdx.x * 256 + threadIdx.x; i < n8; i += stride) {
        long o = i * 8;
        long row = o >> 11, col = o & 2047;
        float4 a = *(const float4*)(src + o);
        float4 b = *(const float4*)(src + o + 4);
        __hip_bfloat16 h8[8] = {
            __float2bfloat16(a.x), __float2bfloat16(a.y),
            __float2bfloat16(a.z), __float2bfloat16(a.w),
            __float2bfloat16(b.x), __float2bfloat16(b.y),
            __float2bfloat16(b.z), __float2bfloat16(b.w)};
        *(uint4*)(dst + ((row * 2 + half) << 11) + col) = *(const uint4*)h8;
    }
}

// x = rms(h, w) -> bf16
__global__ void rms_bf16_kernel(const float* __restrict__ h, const float* __restrict__ w,
                                __hip_bfloat16* __restrict__ o) {
    int s = blockIdx.x;
    const float* row = h + (long)s * D;
    float vals[8], ss = 0.f;
    #pragma unroll
    for (int t = 0; t < 8; ++t) {
        int j = t * 256 + threadIdx.x;
        float v = row[j]; vals[t] = v; ss += v * v;
    }
    ss = blk_sum(ss);
    float r = rsqrtf(ss * (1.f / D) + 1e-6f);
    #pragma unroll
    for (int t = 0; t < 8; ++t) {
        int j = t * 256 + threadIdx.x;
        o[(long)s * D + j] = __float2bfloat16(vals[t] * r * (1.f + w[j]));
    }
}

// h += rms(t, w)   (fallback path only)
__global__ void resid_rms_kernel(float* __restrict__ h, const float* __restrict__ tt,
                                 const float* __restrict__ w) {
    int s = blockIdx.x;
    const float* row = tt + (long)s * D;
    float* hr = h + (long)s * D;
    float vals[8], ss = 0.f;
    #pragma unroll
    for (int t = 0; t < 8; ++t) {
        int j = t * 256 + threadIdx.x;
        float v = row[j]; vals[t] = v; ss += v * v;
    }
    ss = blk_sum(ss);
    float r = rsqrtf(ss * (1.f / D) + 1e-6f);
    #pragma unroll
    for (int t = 0; t < 8; ++t) {
        int j = t * 256 + threadIdx.x;
        hr[j] += vals[t] * r * (1.f + w[j]);
    }
}

// Fused: tv = t0+t1 (bf16 split-K partials); h += rms(tv, w1); xb = rms(h, w2)
// Per-thread contiguous 8 elems -> vector loads/stores.
__global__ void resid2_rms_kernel(float* __restrict__ h, const __hip_bfloat16* __restrict__ t0,
                                  const __hip_bfloat16* __restrict__ t1,
                                  const float* __restrict__ w1, const float* __restrict__ w2,
                                  __hip_bfloat16* __restrict__ xb) {
    int s = blockIdx.x;
    int base = threadIdx.x * 8;
    long o = (long)s * D + base;
    uint4 a0 = *(const uint4*)(t0 + o);
    uint4 a1 = *(const uint4*)(t1 + o);
    const __hip_bfloat16* p0 = (const __hip_bfloat16*)&a0;
    const __hip_bfloat16* p1 = (const __hip_bfloat16*)&a1;
    float vals[8], ss = 0.f;
    #pragma unroll
    for (int j = 0; j < 8; ++j) {
        float v = __bfloat162float(p0[j]) + __bfloat162float(p1[j]);
        vals[j] = v; ss += v * v;
    }
    ss = blk_sum(ss);
    float r = rsqrtf(ss * (1.f / D) + 1e-6f);
    float4 h0 = *(const float4*)(h + o);
    float4 h1 = *(const float4*)(h + o + 4);
    float4 w1a = *(const float4*)(w1 + base);
    float4 w1b = *(const float4*)(w1 + base + 4);
    float hv[8] = {h0.x, h0.y, h0.z, h0.w, h1.x, h1.y, h1.z, h1.w};
    float wv[8] = {w1a.x, w1a.y, w1a.z, w1a.w, w1b.x, w1b.y, w1b.z, w1b.w};
    float ss2 = 0.f;
    #pragma unroll
    for (int j = 0; j < 8; ++j) {
        float nh = hv[j] + vals[j] * r * (1.f + wv[j]);
        hv[j] = nh; ss2 += nh * nh;
    }
    *(float4*)(h + o)     = make_float4(hv[0], hv[1], hv[2], hv[3]);
    *(float4*)(h + o + 4) = make_float4(hv[4], hv[5], hv[6], hv[7]);
    ss2 = blk_sum(ss2);
    float r2 = rsqrtf(ss2 * (1.f / D) + 1e-6f);
    float4 w2a = *(const float4*)(w2 + base);
    float4 w2b = *(const float4*)(w2 + base + 4);
    float wv2[8] = {w2a.x, w2a.y, w2a.z, w2a.w, w2b.x, w2b.y, w2b.z, w2b.w};
    __hip_bfloat16 ob[8];
    #pragma unroll
    for (int j = 0; j < 8; ++j)
        ob[j] = __float2bfloat16(hv[j] * r2 * (1.f + wv2[j]));
    *(uint4*)(xb + o) = *(const uint4*)ob;
}

// in-place RoPE; q|k heads are contiguous (cols 0..3071 of the 4096-wide qkv buffer):
// grid.y = NH+NKV, head hh at col hh*HD. 128 threads per (s, head).
__global__ void rope_kernel(__hip_bfloat16* __restrict__ x, const float* __restrict__ cb,
                            const float* __restrict__ sb, int ldx) {
    int s = blockIdx.x, hh = blockIdx.y, i = threadIdx.x; // i in 0..127
    __hip_bfloat16* p = x + (long)s * ldx + hh * HD;
    float x1 = __bfloat162float(p[i]);
    float x2 = __bfloat162float(p[128 + i]);
    float c = cb[s * 128 + i], sn = sb[s * 128 + i];
    p[i]       = __float2bfloat16(x1 * c - x2 * sn);
    p[128 + i] = __float2bfloat16(x1 * sn + x2 * c);
}

// v rows (stride ldv) -> vT (NKV, HD, S) bf16
__global__ void transpose_v_kernel(const __hip_bfloat16* __restrict__ v,
                                   __hip_bfloat16* __restrict__ vt, int ldv) {
    __shared__ ushort tile[64][65];
    int s0 = blockIdx.x * 64, d0 = blockIdx.y * 64, kv = blockIdx.z;
    const ushort* vin = (const ushort*)v;
    ushort* vout = (ushort*)vt;
    #pragma unroll
    for (int it = 0; it < 4; ++it) {
        int slot = it * 256 + threadIdx.x;
        int r = slot >> 4, c4 = (slot & 15) << 2;
        ushort4 x = *(const ushort4*)(vin + (long)(s0 + r) * ldv + kv * HD + d0 + c4);
        tile[r][c4] = x.x; tile[r][c4 + 1] = x.y; tile[r][c4 + 2] = x.z; tile[r][c4 + 3] = x.w;
    }
    __syncthreads();
    #pragma unroll
    for (int it = 0; it < 4; ++it) {
        int slot = it * 256 + threadIdx.x;
        int rr = slot >> 4, c4 = (slot & 15) << 2;
        ushort4 y;
        y.x = tile[c4][rr]; y.y = tile[c4 + 1][rr]; y.z = tile[c4 + 2][rr]; y.w = tile[c4 + 3][rr];
        *(ushort4*)(vout + (long)kv * HD * S + (long)(d0 + rr) * S + s0 + c4) = y;
    }
}

// scores (NH,S,S) bf16 -> probs bf16: scale, tanh softcap, mask, softmax.
// Writes only chunks inside PV's banded K-range [bandStart, bandEnd) for this row.
__global__ void softmax_kernel(const __hip_bfloat16* __restrict__ sc,
                               __hip_bfloat16* __restrict__ pr, int isLocal) {
    int i = blockIdx.x, hh = blockIdx.y;
    const __hip_bfloat16* row = sc + ((long)hh * S + i) * S;
    __hip_bfloat16* orow = pr + ((long)hh * S + i) * S;
    int lo = isLocal ? max(0, i - (WINDOW - 1)) : 0;
    int bandEnd = ((i >> 7) + 1) << 7;                         // PV reads cols < bandEnd
    int bandStart = isLocal ? max(0, ((i >> 7) - 8) << 7) : 0; // and cols >= bandStart
    float vals[8];
    float m = -3.0e38f;
    #pragma unroll
    for (int t = 0; t < 8; ++t) {
        int j = t * 256 + threadIdx.x;
        bool chunkAny = (t * 256 <= i) && (t * 256 + 255 >= lo);
        if (chunkAny) {
            bool valid = (j <= i) && (j >= lo);
            float v = tanhf(__bfloat162float(row[j]) * (0.0625f / 50.f)) * 50.f;
            vals[t] = valid ? v : -3.0e38f;
            m = fmaxf(m, vals[t]);
        } else {
            vals[t] = -3.0e38f;
        }
    }
    m = blk_max(m);
    float ps[8], ssum = 0.f;
    #pragma unroll
    for (int t = 0; t < 8; ++t) {
        float p = (vals[t] > -1.0e38f) ? __expf(vals[t] - m) : 0.f;
        ps[t] = p; ssum += p;
    }
    ssum = blk_sum(ssum);
    float inv = 1.f / ssum;
    #pragma unroll
    for (int t = 0; t < 8; ++t) {
        int j = t * 256 + threadIdx.x;
        if (t * 256 < bandEnd && t * 256 + 256 > bandStart)
            orow[j] = __float2bfloat16(ps[t] * inv);
    }
}

// gate half *= up half, packed gu[S][16384] (fallback path only)
__global__ void mul_gu_kernel(__hip_bfloat16* __restrict__ gu) {
    long idx = ((long)blockIdx.x * 256 + threadIdx.x) * 8;
    long s = idx >> 13;
    long f = idx & 8191;
    __hip_bfloat16* gp = gu + s * 16384 + f;
    const __hip_bfloat16* up = gu + s * 16384 + 8192 + f;
    uint4 gv = *(const uint4*)gp;
    uint4 uv = *(const uint4*)up;
    const __hip_bfloat16* gb = (const __hip_bfloat16*)&gv;
    const __hip_bfloat16* ub = (const __hip_bfloat16*)&uv;
    __hip_bfloat16 o[8];
    #pragma unroll
    for (int j = 0; j < 8; ++j)
        o[j] = __float2bfloat16(__bfloat162float(gb[j]) * __bfloat162float(ub[j]));
    *(uint4*)gp = *(const uint4*)o;
}

// ---------------- generic pipelined GEMM: C[M,N] = A[M,K] * B[N,K]^T, bf16 ----------------
// Tile BM=WM*MI*16 x BN=WN*NI*16, BK=32, threads T=WM*WN*64 (BM==BN==T/2 required by staging).
// 4 LDS buffers, depth-3 prefetch, 2 sub-phases/K-tile, counted vmcnt(8), setprio around MFMA,
// both-sides XOR swizzle, XCD-chunked 1-D grid remap (nwg % 8 == 0).
// 128^2 (256 thr, 64 KiB LDS -> 2 blocks/CU): activations/attention GEMMs.
// 256^2 (512 thr, 128 KiB): gate|up + LM head (panel reuse fits L3).
// EPI: 0=f32, 1=bf16, 3=tanh(x/30)*30->f32 (LM head),
//      5=interleaved gelu(gate)*up -> bf16 (B rows interleaved wg/wu)
// kMode: 0 none; 1 causal score-tile skip; 2 local score-tile skip; 3 causal PV K-range;
//        4 local PV K-range; 5 split-K over z (bz picks K-half; C offset bz*cBatch)
template<int EPI, int WM, int WN, int MI, int NI>
__global__ __launch_bounds__(WM*WN*64, 2) void gemm_pipe(
    const __hip_bfloat16* __restrict__ A, const __hip_bfloat16* __restrict__ B,
    void* __restrict__ Cv, int K, int lda, int ldb, int ldc,
    long aBatch, long bBatch, long cBatch, int bzDiv, int gx, int kMode) {
    constexpr int T  = WM * WN * 64;
    constexpr int BM = WM * MI * 16;
    constexpr int BN = WN * NI * 16;
    constexpr int AE = BM * 32;
    constexpr int BE = BN * 32;
    __shared__ __hip_bfloat16 lds[4][AE + BE];

    const int tid = threadIdx.x;
    const int nwg = gridDim.x;
    const int orig = blockIdx.x;
    const int wgid = (orig & 7) * (nwg >> 3) + (orig >> 3);
    const int bx = wgid % gx, by = wgid / gx;
    const int bz = blockIdx.z;

    int kstart = 0, kend = K;
    if (kMode == 1) { if (by > bx) return; }
    else if (kMode == 2) { if (by > bx || bx - by >= 9) return; }
    else if (kMode == 3) { kend = min(K, (bx + 1) * BM); }
    else if (kMode == 4) { kend = min(K, (bx + 1) * BM); kstart = max(0, (bx - 1024 / BM) * BM); }
    else if (kMode == 5) { int hk = K >> 1; kstart = bz * hk; kend = kstart + hk; }

    const __hip_bfloat16* Ab = A + (long)bz * aBatch + (long)bx * BM * lda;
    const __hip_bfloat16* Bb = B + (long)(bz / bzDiv) * bBatch + (long)by * BN * ldb;

    const int w = tid >> 6, l = tid & 63;
    const int wm = w / WN, wn = w % WN;
    const int wrow = wm * MI * 16, wcol = wn * NI * 16;
    const int fr = l & 15, g = l >> 4;
    const int sR = tid >> 2;
    const int sc = tid & 3;

    floatx4 acc[MI][NI] = {};
    bf16x8 bfv[NI];
    bf16x8 af[MI / 2];

    auto stageA = [&](int t, int buf) {
        const int k0 = kstart + t * 32;
        #pragma unroll
        for (int i = 0; i < 2; ++i) {
            int row = sR + i * (T / 4);
            int scol = ((sc ^ ((row >> 1) & 3)) << 3);
            __builtin_amdgcn_global_load_lds(
                (kGlb*)(Ab + (long)row * lda + k0 + scol),
                (kLds*)(&lds[buf][0] + tid * 8 + i * (T * 8)), 16, 0, 0);
        }
    };
    auto stageB = [&](int t, int buf) {
        const int k0 = kstart + t * 32;
        #pragma unroll
        for (int i = 0; i < 2; ++i) {
            int row = sR + i * (T / 4);
            int scol = ((sc ^ ((row >> 1) & 3)) << 3);
            __builtin_amdgcn_global_load_lds(
                (kGlb*)(Bb + (long)row * ldb + k0 + scol),
                (kLds*)(&lds[buf][AE] + tid * 8 + i * (T * 8)), 16, 0, 0);
        }
    };

    auto phase0 = [&](int buf, int t3, bool doStage) {
        const char* AsB = (const char*)&lds[buf][0];
        const char* BsB = (const char*)&lds[buf][AE];
        #pragma unroll
        for (int mi = 0; mi < MI / 2; ++mi) {
            int ra = wrow + mi * 16 + fr;
            af[mi] = *(const bf16x8*)(AsB + ra * 64 + ((g ^ ((ra >> 1) & 3)) << 4));
        }
        #pragma unroll
        for (int ni = 0; ni < NI; ++ni) {
            int rb = wcol + ni * 16 + fr;
            bfv[ni] = *(const bf16x8*)(BsB + rb * 64 + ((g ^ ((rb >> 1) & 3)) << 4));
        }
        if (doStage) stageA(t3, t3 & 3);
        __builtin_amdgcn_s_barrier();
        asm volatile("s_waitcnt lgkmcnt(0)" ::: "memory");
        __builtin_amdgcn_sched_barrier(0);
        __builtin_amdgcn_s_setprio(1);
        #pragma unroll
        for (int mi = 0; mi < MI / 2; ++mi)
            #pragma unroll
            for (int ni = 0; ni < NI; ++ni)
                acc[mi][ni] = __builtin_amdgcn_mfma_f32_16x16x32_bf16(af[mi], bfv[ni], acc[mi][ni], 0, 0, 0);
        __builtin_amdgcn_s_setprio(0);
        __builtin_amdgcn_sched_barrier(0);
        __builtin_amdgcn_s_barrier();
    };

    auto phase1 = [&](int buf, int t3, bool doStage, int vm) {
        const char* AsB = (const char*)&lds[buf][0];
        #pragma unroll
        for (int mi = 0; mi < MI / 2; ++mi) {
            int ra = wrow + (MI / 2 + mi) * 16 + fr;
            af[mi] = *(const bf16x8*)(AsB + ra * 64 + ((g ^ ((ra >> 1) & 3)) << 4));
        }
        if (doStage) stageB(t3, t3 & 3);
        if (vm == 8)      asm volatile("s_waitcnt vmcnt(8)" ::: "memory");
        else if (vm == 4) asm volatile("s_waitcnt vmcnt(4)" ::: "memory");
        else if (vm == 0) asm volatile("s_waitcnt vmcnt(0)" ::: "memory");
        __builtin_amdgcn_s_barrier();
        asm volatile("s_waitcnt lgkmcnt(0)" ::: "memory");
        __builtin_amdgcn_sched_barrier(0);
        __builtin_amdgcn_s_setprio(1);
        #pragma unroll
        for (int mi = 0; mi < MI / 2; ++mi)
            #pragma unroll
            for (int ni = 0; ni < NI; ++ni)
                acc[MI / 2 + mi][ni] = __builtin_amdgcn_mfma_f32_16x16x32_bf16(af[mi], bfv[ni], acc[MI / 2 + mi][ni], 0, 0, 0);
        __builtin_amdgcn_s_setprio(0);
        __builtin_amdgcn_sched_barrier(0);
        __builtin_amdgcn_s_barrier();
    };

    const int nt = (kend - kstart) >> 5;
    stageA(0, 0); stageB(0, 0);
    stageA(1, 1); stageB(1, 1);
    stageA(2, 2); stageB(2, 2);
    asm volatile("s_waitcnt vmcnt(8)" ::: "memory");
    __builtin_amdgcn_s_barrier();

    for (int t = 0; t < nt - 3; ++t) {
        const int b = t & 3;
        phase0(b, t + 3, true);
        phase1(b, t + 3, true, 8);
    }
    phase0((nt - 3) & 3, 0, false); phase1((nt - 3) & 3, 0, false, 4);
    phase0((nt - 2) & 3, 0, false); phase1((nt - 2) & 3, 0, false, 0);
    phase0((nt - 1) & 3, 0, false); phase1((nt - 1) & 3, 0, false, -1);

    const long cBase = (long)bz * cBatch + (long)bx * BM * ldc + (long)by * BN;
    const int rg = (l >> 4) * 4;
    #pragma unroll
    for (int mi = 0; mi < MI; ++mi) {
        #pragma unroll
        for (int ni = 0; ni < NI; ++ni) {
            #pragma unroll
            for (int r = 0; r < 4; ++r) {
                int row = wrow + mi * 16 + rg + r;
                int col = wcol + ni * 16 + fr;
                float v = acc[mi][ni][r];
                if constexpr (EPI == 5) {
                    // B rows interleaved: even col = gate (wg), odd col = up (wu).
                    float pv = __shfl_xor(v, 1);   // partner lane: same row, col^1
                    if (!(fr & 1)) {
                        float gg = 0.5f * v * (1.f + tanhf(0.7978845608f * (v + 0.044715f * v * v * v)));
                        long idx5 = ((long)bx * BM + row) * (long)ldc + (long)by * (BN / 2) + (col >> 1);
                        ((__hip_bfloat16*)Cv)[idx5] = __float2bfloat16(gg * pv);
                    }
                } else {
                    long idx = cBase + (long)row * ldc + col;
                    if constexpr (EPI == 0) {
                        ((float*)Cv)[idx] = v;
                    } else if constexpr (EPI == 1) {
                        ((__hip_bfloat16*)Cv)[idx] = __float2bfloat16(v);
                    } else if constexpr (EPI == 3) {
                        ((float*)Cv)[idx] = tanhf(v * (1.f / 30.f)) * 30.f;
                    }
                }
            }
        }
    }
}

// ---------------- fallback GEMM with fp32 B staging (used only if ws too small) ----------------
template<int EPI>
__global__ __launch_bounds__(256) void gemm_f32w(
    const __hip_bfloat16* __restrict__ A, const float* __restrict__ Bv,
    void* __restrict__ Cv, int K, int lda, int ldb, int ldc) {
    __shared__ __hip_bfloat16 As[128][32];
    __shared__ __hip_bfloat16 Bs[128][32];
    const int tid = threadIdx.x;
    const __hip_bfloat16* Ab = A + (long)blockIdx.x * 128 * lda;
    const float* Bb = Bv + (long)blockIdx.y * 128 * ldb;
    const int wid = tid >> 6, lane = tid & 63;
    const int wr = (wid >> 1) * 64, wc = (wid & 1) * 64;
    const int fr = lane & 15;
    const int kb = (lane >> 4) * 8;
    floatx4 acc[4][4] = {};
    for (int k0 = 0; k0 < K; k0 += 32) {
        __syncthreads();
        #pragma unroll
        for (int it = 0; it < 2; ++it) {
            int slot = tid + it * 256;
            int r = slot >> 2, c8 = (slot & 3) * 8;
            *reinterpret_cast<uint4*>(&As[r][c8]) =
                *reinterpret_cast<const uint4*>(Ab + (long)r * lda + k0 + c8);
        }
        #pragma unroll
        for (int it = 0; it < 4; ++it) {
            int slot = tid + it * 256;
            int r = slot >> 3, c4 = (slot & 7) * 4;
            float4 f = *reinterpret_cast<const float4*>(Bb + (long)r * ldb + k0 + c4);
            __hip_bfloat16 t4[4] = {__float2bfloat16(f.x), __float2bfloat16(f.y),
                                    __float2bfloat16(f.z), __float2bfloat16(f.w)};
            *reinterpret_cast<ushort4*>(&Bs[r][c4]) = *reinterpret_cast<const ushort4*>(t4);
        }
        __syncthreads();
        bf16x8 af[4], bfr[4];
        #pragma unroll
        for (int i = 0; i < 4; ++i)
            af[i] = *reinterpret_cast<const bf16x8*>(&As[wr + i * 16 + fr][kb]);
        #pragma unroll
        for (int j = 0; j < 4; ++j)
            bfr[j] = *reinterpret_cast<const bf16x8*>(&Bs[wc + j * 16 + fr][kb]);
        #pragma unroll
        for (int i = 0; i < 4; ++i)
            #pragma unroll
            for (int j = 0; j < 4; ++j)
                acc[i][j] = __builtin_amdgcn_mfma_f32_16x16x32_bf16(af[i], bfr[j], acc[i][j], 0, 0, 0);
    }
    const long cTile = (long)blockIdx.x * 128 * ldc + (long)blockIdx.y * 128;
    const int rg = (lane >> 4) * 4;
    #pragma unroll
    for (int i = 0; i < 4; ++i)
        #pragma unroll
        for (int j = 0; j < 4; ++j)
            #pragma unroll
            for (int r = 0; r < 4; ++r) {
                int row = wr + i * 16 + rg + r;
                int col = wc + j * 16 + fr;
                long idx = cTile + (long)row * ldc + col;
                float v = acc[i][j][r];
                if constexpr (EPI == 0) ((float*)Cv)[idx] = v;
                else if constexpr (EPI == 1) ((__hip_bfloat16*)Cv)[idx] = __float2bfloat16(v);
                else if constexpr (EPI == 2) {
                    float gg = 0.5f * v * (1.f + tanhf(0.7978845608f * (v + 0.044715f * v * v * v)));
                    ((__hip_bfloat16*)Cv)[idx] = __float2bfloat16(gg);
                } else ((float*)Cv)[idx] = tanhf(v * (1.f / 30.f)) * 30.f;
            }
}

// ---------------- host ----------------
extern "C" void kernel_launch(void* const* d_in, const int* in_sizes, int n_in,
                              void* d_out, int out_size, void* d_ws, size_t ws_size,
                              hipStream_t stream) {
    const int*   ids    = (const int*)d_in[0];
    const float* embedW = (const float*)d_in[1];
    const float* wq     = (const float*)d_in[2];
    const float* wk     = (const float*)d_in[3];
    const float* wv     = (const float*)d_in[4];
    const float* wo     = (const float*)d_in[5];
    const float* wg     = (const float*)d_in[6];
    const float* wu     = (const float*)d_in[7];
    const float* wd     = (const float*)d_in[8];
    const float* ln_in  = (const float*)d_in[9];
    const float* ln_pa  = (const float*)d_in[10];
    const float* ln_pf  = (const float*)d_in[11];
    const float* ln_pff = (const float*)d_in[12];
    const float* ln_f   = (const float*)d_in[13];
    const float* w_lm   = (const float*)d_in[14];
    float* out = (float*)d_out;

    char* ws = (char*)d_ws;
    size_t off = 0;
    auto alloc = [&](size_t bytes) -> void* {
        size_t o = (off + 255) & ~(size_t)255;
        off = o + bytes;
        return (void*)(ws + o);
    };

    float* h            = (float*)alloc((size_t)S * D * 4);
    __hip_bfloat16* xb  = (__hip_bfloat16*)alloc((size_t)S * D * 2);
    __hip_bfloat16* qkvb = (__hip_bfloat16*)alloc((size_t)S * 4096 * 2); // q|k|v packed
    __hip_bfloat16* vT  = (__hip_bfloat16*)alloc((size_t)NKV * HD * S * 2);
    __hip_bfloat16* ab  = (__hip_bfloat16*)alloc((size_t)S * NH * HD * 2);
    __hip_bfloat16* tb0 = (__hip_bfloat16*)alloc((size_t)S * D * 2);  // split-K partial 0
    __hip_bfloat16* tb1 = (__hip_bfloat16*)alloc((size_t)S * D * 2);  // split-K partial 1
    float* tmpf         = (float*)alloc((size_t)S * D * 4);           // fallback only
    __hip_bfloat16* guP = (__hip_bfloat16*)alloc((size_t)S * FF * 2); // gelu(gate)*up
    __hip_bfloat16* gu  = (__hip_bfloat16*)alloc((size_t)S * 16384 * 2); // fallback only
    float* cosb         = (float*)alloc((size_t)S * 128 * 4);
    float* sinb         = (float*)alloc((size_t)S * 128 * 4);
    __hip_bfloat16* scores = (__hip_bfloat16*)alloc((size_t)NH * S * S * 2);
    __hip_bfloat16* probs  = (__hip_bfloat16*)alloc((size_t)NH * S * S * 2);

    const long SLq = 2048L * 2048, SLkv = 1024L * 2048, SLff = 8192L * 2048;
    const long nWlm = (long)VOCAB * D;
    __hip_bfloat16* wqkvb = (__hip_bfloat16*)alloc(4L * 4096 * 2048 * 2);
    __hip_bfloat16* wgub  = (__hip_bfloat16*)alloc(4L * 16384 * 2048 * 2); // interleaved wg/wu
    __hip_bfloat16* wob   = (__hip_bfloat16*)alloc(4L * SLq * 2);
    __hip_bfloat16* wdb   = (__hip_bfloat16*)alloc(4L * SLff * 2);
    __hip_bfloat16* wlmb  = (__hip_bfloat16*)alloc(nWlm * 2);
    const bool big = (off <= ws_size);
    (void)in_sizes; (void)n_in; (void)out_size;

    rope_table_kernel<<<dim3(S), dim3(128), 0, stream>>>(cosb, sinb);
    embed_kernel<<<dim3(D / 256, S), dim3(256), 0, stream>>>(ids, embedW, h);

    auto cvt = [&](const float* s, __hip_bfloat16* dp, long n) {
        long n8 = n / 8;
        long want = (n8 + 255) / 256;
        int blocks = (int)(want < 2048 ? want : 2048);
        cvt_bf16_kernel<<<dim3(blocks), dim3(256), 0, stream>>>(s, dp, n8);
    };
    auto cvtI = [&](const float* s, __hip_bfloat16* dp, int half, long n) {
        long n8 = n / 8;
        long want = (n8 + 255) / 256;
        int blocks = (int)(want < 2048 ? want : 2048);
        cvt_inter_kernel<<<dim3(blocks), dim3(256), 0, stream>>>(s, dp, half, n8);
    };
    if (big) {
        // LM-head weights converted up-front (JIT conversion right before the LM GEMM raised
        // its HBM fetch by ~70 MB in round 9 — dirty L2/L3 collided with the GEMM's reads).
        cvt(w_lm, wlmb, nWlm);
    }

    // launchers: p256 = 256x256 2-phase (512 thr, 128 KiB LDS), p128 = 128x128 2-phase (256 thr)
    auto p256 = [&](int epi, const __hip_bfloat16* A, const __hip_bfloat16* B, void* C,
                    int K, int lda, int ldb, int ldc, int gx, int gy) {
        dim3 grid(gx * gy, 1, 1);
        if (epi == 3)
            gemm_pipe<3, 2, 4, 8, 4><<<grid, 512, 0, stream>>>(A, B, C, K, lda, ldb, ldc, 0, 0, 0, 1, gx, 0);
        else
            gemm_pipe<5, 2, 4, 8, 4><<<grid, 512, 0, stream>>>(A, B, C, K, lda, ldb, ldc, 0, 0, 0, 1, gx, 0);
    };
    auto p128 = [&](int epi, const __hip_bfloat16* A, const __hip_bfloat16* B, void* C,
                    int K, int lda, int ldb, int ldc, int gx, int gy, int gz,
                    long aB, long bB, long cB, int bzDiv, int kMode) {
        dim3 grid(gx * gy, 1, gz);
        switch (epi) {
        case 0: gemm_pipe<0, 2, 2, 4, 4><<<grid, 256, 0, stream>>>(A, B, C, K, lda, ldb, ldc, aB, bB, cB, bzDiv, gx, kMode); break;
        default: gemm_pipe<1, 2, 2, 4, 4><<<grid, 256, 0, stream>>>(A, B, C, K, lda, ldb, ldc, aB, bB, cB, bzDiv, gx, kMode); break;
        }
    };

    if (big) {
        // x = rms(h, ln_in[0]) for layer 0 (subsequent layers get xb from the fused kernel)
        rms_bf16_kernel<<<dim3(S), dim3(256), 0, stream>>>(h, ln_in, xb);
        for (int l = 0; l < NLAYER; ++l) {
            int isLocal = (l % 2 == 0) ? 1 : 0;
            // convert this layer's qkv weights just-in-time (L3-hot for the GEMM read)
            cvt(wq + l * SLq,  wqkvb + (size_t)l * 4096 * 2048,                SLq);
            cvt(wk + l * SLkv, wqkvb + (size_t)l * 4096 * 2048 + 2048L * 2048, SLkv);
            cvt(wv + l * SLkv, wqkvb + (size_t)l * 4096 * 2048 + 3072L * 2048, SLkv);
            p128(1, xb, wqkvb + (size_t)l * 4096 * 2048, qkvb, D, D, D, 4096, 16, 32, 1, 0, 0, 0, 1, 0);
            // q-rope + k-rope merged: heads 0..11 cover cols 0..3071 (q then k)
            rope_kernel<<<dim3(S, NH + NKV), dim3(128), 0, stream>>>(qkvb, cosb, sinb, 4096);
            transpose_v_kernel<<<dim3(S / 64, HD / 64, NKV), 256, 0, stream>>>(qkvb + 3072, vT, 4096);
            // scores = q @ k^T per head (bf16 out), masked-tile skip
            p128(1, qkvb, qkvb + 2048, scores, HD, 4096, 4096, S, 16, 16, NH,
                 (long)HD, (long)HD, (long)S * S, 2, isLocal ? 2 : 1);
            softmax_kernel<<<dim3(S, NH), dim3(256), 0, stream>>>(scores, probs, isLocal);
            // a = probs @ vT, K-range restricted to valid band
            p128(1, probs, vT, ab, S, S, S, NH * HD, 16, 2, NH,
                 (long)S * S, (long)HD * S, (long)HD, 2, isLocal ? 4 : 3);
            // attn out projection, split-K=2 (512 blocks -> 2 blocks/CU), bf16 partials
            cvt(wo + l * SLq, wob + (size_t)l * SLq, SLq);
            p128(1, ab, wob + (size_t)l * SLq, tb0, NH * HD, NH * HD, NH * HD, D,
                 16, 16, 2, 0, 0, (long)S * D, 1, 5);
            // h += rms(tb0+tb1, ln_pa); xb = rms(h, ln_pf)
            resid2_rms_kernel<<<dim3(S), dim3(256), 0, stream>>>(
                h, tb0, tb1, ln_pa + l * D, ln_pf + l * D, xb);
            // fused gate|up (interleaved rows), 256^2 tile; writes gelu(gate)*up -> guP [S][8192]
            cvtI(wg + l * SLff, wgub + (size_t)l * 16384 * 2048, 0, SLff);
            cvtI(wu + l * SLff, wgub + (size_t)l * 16384 * 2048, 1, SLff);
            p256(5, xb, wgub + (size_t)l * 16384 * 2048, guP, D, D, D, FF, 8, 64);
            // down projection, split-K=2, bf16 partials
            cvt(wd + l * SLff, wdb + (size_t)l * SLff, SLff);
            p128(1, guP, wdb + (size_t)l * SLff, tb0, FF, FF, FF, D,
                 16, 16, 2, 0, 0, (long)S * D, 1, 5);
            // h += rms(tb0+tb1, ln_pff); xb = rms(h, next-op weight)
            const float* wNext = (l < NLAYER - 1) ? (ln_in + (l + 1) * D) : ln_f;
            resid2_rms_kernel<<<dim3(S), dim3(256), 0, stream>>>(
                h, tb0, tb1, ln_pff + l * D, wNext, xb);
        }
        // LM head: 256^2 tile, 8 x 125 = 1000 blocks, tanh(x/30)*30 -> f32
        p256(3, xb, wlmb, out, D, D, D, VOCAB, 8, VOCAB / 256);
    } else {
        for (int l = 0; l < NLAYER; ++l) {
            int isLocal = (l % 2 == 0) ? 1 : 0;
            rms_bf16_kernel<<<dim3(S), dim3(256), 0, stream>>>(h, ln_in + l * D, xb);
            gemm_f32w<1><<<dim3(16, 16), 256, 0, stream>>>(xb, wq + l * SLq, qkvb, D, D, D, 4096);
            gemm_f32w<1><<<dim3(16, 8), 256, 0, stream>>>(xb, wk + l * SLkv, qkvb + 2048, D, D, D, 4096);
            gemm_f32w<1><<<dim3(16, 8), 256, 0, stream>>>(xb, wv + l * SLkv, qkvb + 3072, D, D, D, 4096);
            rope_kernel<<<dim3(S, NH + NKV), dim3(128), 0, stream>>>(qkvb, cosb, sinb, 4096);
            transpose_v_kernel<<<dim3(S / 64, HD / 64, NKV), 256, 0, stream>>>(qkvb + 3072, vT, 4096);
            p128(1, qkvb, qkvb + 2048, scores, HD, 4096, 4096, S, 16, 16, NH,
                 (long)HD, (long)HD, (long)S * S, 2, isLocal ? 2 : 1);
            softmax_kernel<<<dim3(S, NH), dim3(256), 0, stream>>>(scores, probs, isLocal);
            p128(1, probs, vT, ab, S, S, S, NH * HD, 16, 2, NH,
                 (long)S * S, (long)HD * S, (long)HD, 2, isLocal ? 4 : 3);
            gemm_f32w<0><<<dim3(16, 16), 256, 0, stream>>>(ab, wo + l * SLq, tmpf, NH * HD, NH * HD, NH * HD, D);
            resid_rms_kernel<<<dim3(S), dim3(256), 0, stream>>>(h, tmpf, ln_pa + l * D);
            rms_bf16_kernel<<<dim3(S), dim3(256), 0, stream>>>(h, ln_pf + l * D, xb);
            gemm_f32w<2><<<dim3(16, 64), 256, 0, stream>>>(xb, wg + l * SLff, gu, D, D, D, 16384);
            gemm_f32w<1><<<dim3(16, 64), 256, 0, stream>>>(xb, wu + l * SLff, gu + 8192, D, D, D, 16384);
            mul_gu_kernel<<<dim3((S * FF) / (256 * 8)), 256, 0, stream>>>(gu);
            gemm_f32w<0><<<dim3(16, 16), 256, 0, stream>>>(gu, wd + l * SLff, tmpf, FF, 16384, FF, D);
            resid_rms_kernel<<<dim3(S), dim3(256), 0, stream>>>(h, tmpf, ln_pff + l * D);
        }
        rms_bf16_kernel<<<dim3(S), dim3(256), 0, stream>>>(h, ln_f, xb);
        gemm_f32w<3><<<dim3(16, VOCAB / 128), 256, 0, stream>>>(xb, w_lm, out, D, D, D, VOCAB);
    }
}